// Round 4
// baseline (163.793 us; speedup 1.0000x reference)
//
#include <hip/hip_runtime.h>

typedef __attribute__((ext_vector_type(8))) __bf16 bf16x8;
typedef __attribute__((ext_vector_type(4))) float f32x4;

#define MFMA16(A,B,C) __builtin_amdgcn_mfma_f32_16x16x32_bf16(A,B,C,0,0,0)

// ---- ws layout in __bf16 elements ----
#define WS_W3N 0         // [4096][64]  folded node W3 (incl. Lns/Lnv, all scales)
#define WS_W3E 262144    // [4096][64]
#define WS_TN  524288    // [4][32][64] node tp weights^T * alpha
#define WS_TE  532480    // [4][32][32] edge tp weights^T * alpha
#define WS_M1N 536576    // [64][32] (k<8 real, rest 0) * 1/sqrt(8)
#define WS_M2N 538624    // [64][64] * 1/8
#define WS_M1E 542720
#define WS_M2E 544768
#define WS_CNT 548864    // elements (=1097728 bytes)

__global__ void prep_kernel(
    const float* __restrict__ Wn1, const float* __restrict__ Wn2,
    const float* __restrict__ Wn3, const float* __restrict__ Wn4,
    const float* __restrict__ We1, const float* __restrict__ We2,
    const float* __restrict__ We3, const float* __restrict__ We4,
    const float* __restrict__ Mn1, const float* __restrict__ Mn2, const float* __restrict__ Mn3,
    const float* __restrict__ Me1, const float* __restrict__ Me2, const float* __restrict__ Me3,
    const float* __restrict__ Lns, const float* __restrict__ Lnv,
    const float* __restrict__ Les, const float* __restrict__ Lev,
    __bf16* __restrict__ ws)
{
  int idx = blockIdx.x * 256 + threadIdx.x;
  const float c1 = 0.0027621359f;            // 1/(8*8*sqrt(32))
  const float an = 0.125f;                   // node tp alpha (1/sqrt(64))
  const float ae = 0.17677669529663687f;     // edge tp alpha (1/sqrt(32))
  const float r3 = 0.5773502691896258f;      // 1/sqrt(3)
  const float m1s = 0.35355339059327373f;    // 1/sqrt(8)
  const float m2s = 0.125f;                  // 1/sqrt(64)
  if (idx < 524288) {
    int br = idx >> 18;
    int rem = idx & 262143;
    int j = rem >> 12;
    int kc = rem & 4095;
    int vh = kc >> 11;
    int r2 = kc & 2047;
    int u = r2 >> 5, wp = r2 & 31;
    const float* M3 = br ? Me3 : Mn3;
    const float* L  = vh ? (br ? Lev : Lnv) : (br ? Les : Lns);
    const float* mrow = M3 + (size_t)j * 4096 + vh * 2048 + u * 32;
    float s = 0.f;
    #pragma unroll
    for (int w = 0; w < 32; ++w) s += mrow[w] * L[w * 32 + wp];
    ws[(br ? WS_W3E : WS_W3N) + (size_t)kc * 64 + j] = (__bf16)(s * c1);
  } else if (idx < 524288 + 8192) {
    int t = idx - 524288;
    int i = t >> 11; int r = t & 2047; int w = r >> 6; int u = r & 63;
    const float* W = (i == 0) ? Wn1 : (i == 1) ? Wn2 : (i == 2) ? Wn3 : Wn4;
    float sc = an * ((i == 3) ? r3 : 1.f);
    ws[WS_TN + t] = (__bf16)(W[u * 32 + w] * sc);
  } else if (idx < 524288 + 12288) {
    int t = idx - 532480;
    int i = t >> 10; int r = t & 1023; int w = r >> 5; int u = r & 31;
    const float* W = (i == 0) ? We1 : (i == 1) ? We2 : (i == 2) ? We3 : We4;
    float sc = ae * ((i == 3) ? r3 : 1.f);
    ws[WS_TE + t] = (__bf16)(W[u * 32 + w] * sc);
  } else if (idx < 536576 + 2048) {
    int t = idx - 536576;
    int j = t >> 5, k = t & 31;
    ws[WS_M1N + t] = (__bf16)((k < 8) ? Mn1[k * 64 + j] * m1s : 0.f);
  } else if (idx < 538624 + 4096) {
    int t = idx - 538624;
    int j2 = t >> 6, j = t & 63;
    ws[WS_M2N + t] = (__bf16)(Mn2[j * 64 + j2] * m2s);
  } else if (idx < 542720 + 2048) {
    int t = idx - 542720;
    int j = t >> 5, k = t & 31;
    ws[WS_M1E + t] = (__bf16)((k < 8) ? Me1[k * 64 + j] * m1s : 0.f);
  } else if (idx < 544768 + 4096) {
    int t = idx - 544768;
    int j2 = t >> 6, j = t & 63;
    ws[WS_M2E + t] = (__bf16)(Me2[j * 64 + j2] * m2s);
  }
}

__device__ __forceinline__ float siluf(float x) { return x / (1.0f + __expf(-x)); }
__device__ __forceinline__ unsigned int pk2(float lo, float hi) {
  unsigned short a = __builtin_bit_cast(unsigned short, (__bf16)lo);
  unsigned short b = __builtin_bit_cast(unsigned short, (__bf16)hi);
  return (unsigned int)a | ((unsigned int)b << 16);
}
__device__ __forceinline__ float bflo(unsigned int v) { return __builtin_bit_cast(float, (unsigned int)(v << 16)); }
__device__ __forceinline__ float bfhi(unsigned int v) { return __builtin_bit_cast(float, (unsigned int)(v & 0xffff0000u)); }

// 32 edges per WG. LDS map (24576 B / WG):
//   [0,16384)      coeff: wave w at w*4096 : [u_local 16][e 32] * 8B (bf16x4)
//                  (first 2KB of own region doubles as MLP h1 scratch, dead
//                   before q_phase writes coefficients over it)
//   [16384,20480)  h2n  : [e 32][64 j bf16, 16B-granule XOR swizzled]
//   [20480,24576)  h2e
// After mains, [0,16384) becomes the reduction buffer R1
// (32 e x 512B: granule gs=c>>2 holds S[c], gs=8+m*8+(w>>2) holds V[m][w]).
__global__ __launch_bounds__(256, 4) void fused_kernel(
    const float* __restrict__ nsrc, const float* __restrict__ ndst,
    const float* __restrict__ efeat, const float* __restrict__ lenv,
    const float* __restrict__ escal,
    const __bf16* __restrict__ ws,
    float* __restrict__ out, int E)
{
  __shared__ __align__(16) char lds[24576];
  const int tid = threadIdx.x;
  const int wave = tid >> 6, l = tid & 63;
  const int lg = l >> 4, li = l & 15;
  const int ebase = blockIdx.x * 32;

  char* coeffw = lds + wave * 4096;
  char* h2n = lds + 16384;
  char* h2e = lds + 20480;

  const int rt_role = wave & 1;   // q-row tile role
  const int half = wave >> 1;     // 0: q1,q2  1: q3,q4

  // ---------------- MLP: wave = (branch<<1) | ct, one e-tile each ----------------
  {
    const int br = wave >> 1;
    const int ct = wave & 1;
    const __bf16* M1 = ws + (br ? WS_M1E : WS_M1N);
    const __bf16* M2 = ws + (br ? WS_M2E : WS_M2N);
    char* h2buf = br ? h2e : h2n;
    char* h1s = coeffw;           // private scratch (hl in [0,16))
    int el = ct * 16 + li;
    int hl = li;
    int ee = min(ebase + el, E - 1);
    bf16x8 bx;
    #pragma unroll
    for (int i = 0; i < 8; ++i) bx[i] = (__bf16)0.f;
    if (lg == 0) {
      const float* xp = escal + (size_t)ee * 8;
      float4 t0 = *(const float4*)(xp);
      float4 t1 = *(const float4*)(xp + 4);
      bx[0]=(__bf16)t0.x; bx[1]=(__bf16)t0.y; bx[2]=(__bf16)t0.z; bx[3]=(__bf16)t0.w;
      bx[4]=(__bf16)t1.x; bx[5]=(__bf16)t1.y; bx[6]=(__bf16)t1.z; bx[7]=(__bf16)t1.w;
    }
    f32x4 hc[4];
    #pragma unroll
    for (int rt = 0; rt < 4; ++rt) {
      bf16x8 a = *(const bf16x8*)(M1 + (rt * 16 + li) * 32 + lg * 8);
      f32x4 c = {0.f, 0.f, 0.f, 0.f};
      hc[rt] = MFMA16(a, bx, c);
    }
    #pragma unroll
    for (int rt = 0; rt < 4; ++rt) {
      int j0 = rt * 16 + lg * 4;
      int g = j0 >> 3;
      int addr = hl * 128 + (((g ^ (hl & 7)) << 4)) + (j0 & 7) * 2;
      uint2 wv; wv.x = pk2(siluf(hc[rt][0]), siluf(hc[rt][1]));
      wv.y = pk2(siluf(hc[rt][2]), siluf(hc[rt][3]));
      *(uint2*)(h1s + addr) = wv;
    }
    f32x4 h2c[4];
    #pragma unroll
    for (int rt = 0; rt < 4; ++rt) { f32x4 z = {0.f,0.f,0.f,0.f}; h2c[rt] = z; }
    #pragma unroll
    for (int kj = 0; kj < 2; ++kj) {
      bf16x8 b = *(const bf16x8*)(h1s + hl * 128 + (((kj * 4 + lg) ^ (hl & 7)) << 4));
      #pragma unroll
      for (int rt = 0; rt < 4; ++rt) {
        bf16x8 a = *(const bf16x8*)(M2 + (rt * 16 + li) * 64 + kj * 32 + lg * 8);
        h2c[rt] = MFMA16(a, b, h2c[rt]);
      }
    }
    #pragma unroll
    for (int rt = 0; rt < 4; ++rt) {
      int j0 = rt * 16 + lg * 4;
      int g = j0 >> 3;
      int addr = el * 128 + (((g ^ (el & 7)) << 4)) + (j0 & 7) * 2;
      uint2 wv; wv.x = pk2(siluf(h2c[rt][0]), siluf(h2c[rt][1]));
      wv.y = pk2(siluf(h2c[rt][2]), siluf(h2c[rt][3]));
      *(uint2*)(h2buf + addr) = wv;
    }
  }

  // ---------------- tp coefficient GEMMs -> coeff LDS ----------------
  auto q_phase = [&](const float* f0, const float* f1, int nk, const __bf16* T, int ustride) {
    for (int ct = 0; ct < 2; ++ct) {
      int el = ct * 16 + li;
      int ee = min(ebase + el, E - 1);
      const float4 le = *(const float4*)(lenv + (size_t)ee * 4);
      const size_t erow = (size_t)ee * 128;
      if (half == 0) {
        f32x4 q1c = {0.f,0.f,0.f,0.f}, q2c = {0.f,0.f,0.f,0.f};
        for (int kj = 0; kj < nk; ++kj) {
          const float* fp = (kj ? f1 : f0) + erow + lg * 8;
          float4 t0 = *(const float4*)(fp);
          float4 t1 = *(const float4*)(fp + 4);
          bf16x8 b;
          b[0]=(__bf16)t0.x; b[1]=(__bf16)t0.y; b[2]=(__bf16)t0.z; b[3]=(__bf16)t0.w;
          b[4]=(__bf16)t1.x; b[5]=(__bf16)t1.y; b[6]=(__bf16)t1.z; b[7]=(__bf16)t1.w;
          bf16x8 a1 = *(const bf16x8*)(T + (rt_role * 16 + li) * ustride + kj * 32 + lg * 8);
          bf16x8 a2 = *(const bf16x8*)(T + 32 * ustride + (rt_role * 16 + li) * ustride + kj * 32 + lg * 8);
          q1c = MFMA16(a1, b, q1c);
          q2c = MFMA16(a2, b, q2c);
        }
        #pragma unroll
        for (int r = 0; r < 4; ++r) {
          uint2 cw;
          cw.x = pk2(q1c[r] * le.x, q2c[r] * le.y);
          cw.y = pk2(q2c[r] * le.z, q2c[r] * le.w);
          *(uint2*)(coeffw + (lg * 4 + r) * 256 + el * 8) = cw;
        }
      } else {
        f32x4 q30 = {0.f,0.f,0.f,0.f}, q31 = {0.f,0.f,0.f,0.f}, q32 = {0.f,0.f,0.f,0.f}, q4c = {0.f,0.f,0.f,0.f};
        for (int kj = 0; kj < nk; ++kj) {
          const float* fp = (kj ? f1 : f0) + erow + 32 + lg * 24;
          float v[24];
          #pragma unroll
          for (int q = 0; q < 6; ++q) {
            float4 t = *(const float4*)(fp + q * 4);
            v[q*4] = t.x; v[q*4+1] = t.y; v[q*4+2] = t.z; v[q*4+3] = t.w;
          }
          bf16x8 b0, b1, b2, bd;
          #pragma unroll
          for (int i = 0; i < 8; ++i) {
            b0[i] = (__bf16)v[3*i]; b1[i] = (__bf16)v[3*i+1]; b2[i] = (__bf16)v[3*i+2];
            bd[i] = (__bf16)(v[3*i] * le.y + v[3*i+1] * le.z + v[3*i+2] * le.w);
          }
          bf16x8 a3 = *(const bf16x8*)(T + 2 * 32 * ustride + (rt_role * 16 + li) * ustride + kj * 32 + lg * 8);
          bf16x8 a4 = *(const bf16x8*)(T + 3 * 32 * ustride + (rt_role * 16 + li) * ustride + kj * 32 + lg * 8);
          q30 = MFMA16(a3, b0, q30); q31 = MFMA16(a3, b1, q31); q32 = MFMA16(a3, b2, q32);
          q4c = MFMA16(a4, bd, q4c);
        }
        #pragma unroll
        for (int r = 0; r < 4; ++r) {
          uint2 cw;
          cw.x = pk2(q4c[r], q30[r] * le.x);
          cw.y = pk2(q31[r] * le.x, q32[r] * le.x);
          *(uint2*)(coeffw + (lg * 4 + r) * 256 + el * 8) = cw;
        }
      }
    }
  };

  // ---------------- main GEMM + contraction ----------------
  f32x4 aS0[2], aV0[2][3], aS1[2], aV1[2][3];

  auto load_af = [&](const __bf16* W3T, int u, int rt, bf16x8 (&af)[2][2]) {
    const __bf16* ab = W3T + ((size_t)(u * 32 + rt * 16) + li) * 64 + lg * 8;
    #pragma unroll
    for (int gv = 0; gv < 2; ++gv)
      #pragma unroll
      for (int kj = 0; kj < 2; ++kj)
        af[gv][kj] = *(const bf16x8*)(ab + gv * 131072 + kj * 32);
  };

  auto compute_ul = [&](const bf16x8 (&af)[2][2], int ul, const bf16x8 (&bb)[2][2],
                        f32x4 (&aS)[2], f32x4 (&aV)[2][3]) {
    #pragma unroll
    for (int ct = 0; ct < 2; ++ct) {
      uint2 cf = *(const uint2*)(coeffw + ul * 256 + (ct * 16 + li) * 8);
      float ms = bflo(cf.x), m0 = bfhi(cf.x), m1 = bflo(cf.y), m2 = bfhi(cf.y);
      f32x4 c = {0.f,0.f,0.f,0.f};
      c = MFMA16(af[0][0], bb[ct][0], c);
      c = MFMA16(af[0][1], bb[ct][1], c);
      aS[ct] += ms * c;
      f32x4 d = {0.f,0.f,0.f,0.f};
      d = MFMA16(af[1][0], bb[ct][0], d);
      d = MFMA16(af[1][1], bb[ct][1], d);
      aV[ct][0] += m0 * d;
      aV[ct][1] += m1 * d;
      aV[ct][2] += m2 * d;
    }
  };

  auto run_pass = [&](const __bf16* W3T, const bf16x8 (&bb)[2][2], int rt,
                      f32x4 (&aS)[2], f32x4 (&aV)[2][3]) {
    const int ubase = wave << 4;
    bf16x8 afA[2][2], afB[2][2];
    load_af(W3T, ubase, rt, afA);
    #pragma unroll 1
    for (int up = 0; up < 8; ++up) {
      load_af(W3T, ubase + 2 * up + 1, rt, afB);
      compute_ul(afA, 2 * up, bb, aS, aV);
      load_af(W3T, ubase + min(2 * up + 2, 15), rt, afA);  // last load redundant
      compute_ul(afB, 2 * up + 1, bb, aS, aV);
    }
  };

  auto main_phase = [&](const __bf16* W3T, char* h2buf) {
    bf16x8 bb[2][2];
    #pragma unroll
    for (int ct = 0; ct < 2; ++ct)
      #pragma unroll
      for (int kj = 0; kj < 2; ++kj) {
        int el = ct * 16 + li;
        bb[ct][kj] = *(const bf16x8*)(h2buf + el * 128 + (((kj * 4 + lg) ^ (el & 7)) << 4));
      }
    run_pass(W3T, bb, 0, aS0, aV0);
    run_pass(W3T, bb, 1, aS1, aV1);
  };

  // node branch
  q_phase(nsrc, ndst, 2, ws + WS_TN, 64);
  __syncthreads();                       // h2n/h2e + all coeffs ready

  #pragma unroll
  for (int ct = 0; ct < 2; ++ct) {
    f32x4 z = {0.f,0.f,0.f,0.f};
    aS0[ct] = z; aV0[ct][0] = z; aV0[ct][1] = z; aV0[ct][2] = z;
    aS1[ct] = z; aV1[ct][0] = z; aV1[ct][1] = z; aV1[ct][2] = z;
  }

  main_phase(ws + WS_W3N, h2n);
  // edge branch (coeff buffer is wave-private; no barrier needed)
  q_phase(efeat, efeat, 1, ws + WS_TE, 32);
  main_phase(ws + WS_W3E, h2e);
  __syncthreads();                       // all mains done; coeff region -> R1

  // ---------------- serial cross-wave reduction into R1 (f32x4 granules) ----------------
  char* R1 = lds;
  auto rmw = [&](bool add) {
    #pragma unroll
    for (int ct = 0; ct < 2; ++ct) {
      int e = ct * 16 + li;
      char* ep = R1 + e * 512;
      #pragma unroll
      for (int rt = 0; rt < 2; ++rt) {
        f32x4 s = rt ? aS1[ct] : aS0[ct];
        int gs = rt * 4 + lg;
        char* p = ep + ((gs ^ (e & 7)) << 4);
        if (add) s += *(const f32x4*)p;
        *(f32x4*)p = s;
        #pragma unroll
        for (int m = 0; m < 3; ++m) {
          f32x4 x = rt ? aV1[ct][m] : aV0[ct][m];
          int gv = 8 + m * 8 + rt * 4 + lg;
          char* q = ep + ((gv ^ (e & 7)) << 4);
          if (add) x += *(const f32x4*)q;
          *(f32x4*)q = x;
        }
      }
    }
  };
  if (wave == 0) rmw(false);
  __syncthreads();
  if (wave == 1) rmw(true);
  __syncthreads();
  if (wave == 2) rmw(true);
  __syncthreads();
  if (wave == 3) rmw(true);
  __syncthreads();

  // ---------------- coalesced store (permute [S | V[m][c]] -> [s | v[c][m]]) ----------------
  #pragma unroll
  for (int it = 0; it < 4; ++it) {
    int chunk = it * 256 + tid;        // 1024 float4 chunks = 32 edges * 128 floats
    int e = chunk >> 5, c4 = chunk & 31;
    f32x4 v;
    #pragma unroll
    for (int q = 0; q < 4; ++q) {
      int f = c4 * 4 + q;
      int g, wd;
      if (f < 32) { g = f >> 2; wd = f & 3; }
      else { int t = f - 32; int w = t / 3; int m = t - w * 3; g = 8 + m * 8 + (w >> 2); wd = w & 3; }
      v[q] = *(const float*)(R1 + e * 512 + ((g ^ (e & 7)) << 4) + wd * 4);
    }
    int ge = ebase + e;
    if (ge < E) *(f32x4*)(out + (size_t)ge * 128 + c4 * 4) = v;
  }
}

extern "C" void kernel_launch(void* const* d_in, const int* in_sizes, int n_in,
                              void* d_out, int out_size, void* d_ws, size_t ws_size,
                              hipStream_t stream) {
  const float* nsrc  = (const float*)d_in[0];
  const float* ndst  = (const float*)d_in[1];
  const float* efeat = (const float*)d_in[2];
  const float* lenv  = (const float*)d_in[3];
  const float* escal = (const float*)d_in[4];
  const float* Wn1 = (const float*)d_in[5];
  const float* Wn2 = (const float*)d_in[6];
  const float* Wn3 = (const float*)d_in[7];
  const float* Wn4 = (const float*)d_in[8];
  const float* We1 = (const float*)d_in[9];
  const float* We2 = (const float*)d_in[10];
  const float* We3 = (const float*)d_in[11];
  const float* We4 = (const float*)d_in[12];
  const float* Mn1 = (const float*)d_in[13];
  const float* Mn2 = (const float*)d_in[14];
  const float* Mn3 = (const float*)d_in[15];
  const float* Me1 = (const float*)d_in[16];
  const float* Me2 = (const float*)d_in[17];
  const float* Me3 = (const float*)d_in[18];
  const float* Lns = (const float*)d_in[19];
  const float* Lnv = (const float*)d_in[20];
  const float* Les = (const float*)d_in[21];
  const float* Lev = (const float*)d_in[22];
  (void)n_in; (void)ws_size;

  int E = in_sizes[0] / 128;
  __bf16* ws = (__bf16*)d_ws;
  float* outp = (float*)d_out;
  (void)out_size;

  int nprep = (WS_CNT + 255) / 256;
  hipLaunchKernelGGL(prep_kernel, dim3(nprep), dim3(256), 0, stream,
                     Wn1, Wn2, Wn3, Wn4, We1, We2, We3, We4,
                     Mn1, Mn2, Mn3, Me1, Me2, Me3,
                     Lns, Lnv, Les, Lev, ws);

  int nwg = (E + 31) / 32;
  hipLaunchKernelGGL(fused_kernel, dim3(nwg), dim3(256), 0, stream,
                     nsrc, ndst, efeat, lenv, escal, ws, outp, E);
}

// Round 5
// 154.606 us; speedup vs baseline: 1.0594x; 1.0594x over previous
//
#include <hip/hip_runtime.h>

typedef __attribute__((ext_vector_type(8))) __bf16 bf16x8;
typedef __attribute__((ext_vector_type(4))) float f32x4;

#define MFMA16(A,B,C) __builtin_amdgcn_mfma_f32_16x16x32_bf16(A,B,C,0,0,0)

// ---- ws layout in __bf16 elements ----
#define WS_W3N 0         // [4096][64]  folded node W3 (incl. Lns/Lnv, all scales)
#define WS_W3E 262144    // [4096][64]
#define WS_TN  524288    // [4][32][64] node tp weights^T * alpha
#define WS_TE  532480    // [4][32][32] edge tp weights^T * alpha
#define WS_M1N 536576    // [64][32] (k<8 real, rest 0) * 1/sqrt(8)
#define WS_M2N 538624    // [64][64] * 1/8
#define WS_M1E 542720
#define WS_M2E 544768
#define WS_CNT 548864    // elements (=1097728 bytes)

__global__ void prep_kernel(
    const float* __restrict__ Wn1, const float* __restrict__ Wn2,
    const float* __restrict__ Wn3, const float* __restrict__ Wn4,
    const float* __restrict__ We1, const float* __restrict__ We2,
    const float* __restrict__ We3, const float* __restrict__ We4,
    const float* __restrict__ Mn1, const float* __restrict__ Mn2, const float* __restrict__ Mn3,
    const float* __restrict__ Me1, const float* __restrict__ Me2, const float* __restrict__ Me3,
    const float* __restrict__ Lns, const float* __restrict__ Lnv,
    const float* __restrict__ Les, const float* __restrict__ Lev,
    __bf16* __restrict__ ws)
{
  int idx = blockIdx.x * 256 + threadIdx.x;
  const float c1 = 0.0027621359f;            // 1/(8*8*sqrt(32))
  const float an = 0.125f;                   // node tp alpha (1/sqrt(64))
  const float ae = 0.17677669529663687f;     // edge tp alpha (1/sqrt(32))
  const float r3 = 0.5773502691896258f;      // 1/sqrt(3)
  const float m1s = 0.35355339059327373f;    // 1/sqrt(8)
  const float m2s = 0.125f;                  // 1/sqrt(64)
  if (idx < 524288) {
    int br = idx >> 18;
    int rem = idx & 262143;
    int j = rem >> 12;
    int kc = rem & 4095;
    int vh = kc >> 11;
    int r2 = kc & 2047;
    int u = r2 >> 5, wp = r2 & 31;
    const float* M3 = br ? Me3 : Mn3;
    const float* L  = vh ? (br ? Lev : Lnv) : (br ? Les : Lns);
    const float* mrow = M3 + (size_t)j * 4096 + vh * 2048 + u * 32;
    float s = 0.f;
    #pragma unroll
    for (int w = 0; w < 32; ++w) s += mrow[w] * L[w * 32 + wp];
    ws[(br ? WS_W3E : WS_W3N) + (size_t)kc * 64 + j] = (__bf16)(s * c1);
  } else if (idx < 524288 + 8192) {
    int t = idx - 524288;
    int i = t >> 11; int r = t & 2047; int w = r >> 6; int u = r & 63;
    const float* W = (i == 0) ? Wn1 : (i == 1) ? Wn2 : (i == 2) ? Wn3 : Wn4;
    float sc = an * ((i == 3) ? r3 : 1.f);
    ws[WS_TN + t] = (__bf16)(W[u * 32 + w] * sc);
  } else if (idx < 524288 + 12288) {
    int t = idx - 532480;
    int i = t >> 10; int r = t & 1023; int w = r >> 5; int u = r & 31;
    const float* W = (i == 0) ? We1 : (i == 1) ? We2 : (i == 2) ? We3 : We4;
    float sc = ae * ((i == 3) ? r3 : 1.f);
    ws[WS_TE + t] = (__bf16)(W[u * 32 + w] * sc);
  } else if (idx < 536576 + 2048) {
    int t = idx - 536576;
    int j = t >> 5, k = t & 31;
    ws[WS_M1N + t] = (__bf16)((k < 8) ? Mn1[k * 64 + j] * m1s : 0.f);
  } else if (idx < 538624 + 4096) {
    int t = idx - 538624;
    int j2 = t >> 6, j = t & 63;
    ws[WS_M2N + t] = (__bf16)(Mn2[j * 64 + j2] * m2s);
  } else if (idx < 542720 + 2048) {
    int t = idx - 542720;
    int j = t >> 5, k = t & 31;
    ws[WS_M1E + t] = (__bf16)((k < 8) ? Me1[k * 64 + j] * m1s : 0.f);
  } else if (idx < 544768 + 4096) {
    int t = idx - 544768;
    int j2 = t >> 6, j = t & 63;
    ws[WS_M2E + t] = (__bf16)(Me2[j * 64 + j2] * m2s);
  }
}

__device__ __forceinline__ float siluf(float x) { return x / (1.0f + __expf(-x)); }
__device__ __forceinline__ unsigned int pk2(float lo, float hi) {
  unsigned short a = __builtin_bit_cast(unsigned short, (__bf16)lo);
  unsigned short b = __builtin_bit_cast(unsigned short, (__bf16)hi);
  return (unsigned int)a | ((unsigned int)b << 16);
}
__device__ __forceinline__ float bflo(unsigned int v) { return __builtin_bit_cast(float, (unsigned int)(v << 16)); }
__device__ __forceinline__ float bfhi(unsigned int v) { return __builtin_bit_cast(float, (unsigned int)(v & 0xffff0000u)); }

// 64 edges per WG, 512 threads (8 waves). LDS map (49152 B / WG):
//   [0,32768)      coeff: [u 64][e 64] * 8B (bf16x4: ms,m0,m1,m2)
//                  (first 16KB doubles as MLP h1 scratch, wave*2048, dead
//                   before q_phase writes coefficients over it)
//   [32768,40960)  h2n  : [e 64][64 j bf16, 16B-granule XOR swizzled]
//   [40960,49152)  h2e
// After mains, [0,32768) becomes the reduction buffer R1
// (64 e x 512B: granule gs=c>>2 holds S[c], gs=8+m*8+(w>>2) holds V[m][w]).
//
// Wave roles (wave = tid>>6):
//   MLP :  br = wave>>2,        ctm = wave&3        (one 16-e tile each)
//   q   :  half=(wave>>2)&1, rt_role=(wave>>1)&1, eh=wave&1  (16 u x 32 e)
//   main:  uh = (wave>>2)&1, rtw=(wave>>1)&1,  eh=wave&1     (32 u x 16 w x 32 e)
//   red :  uh=0 waves write, uh=1 waves add.
__global__ __launch_bounds__(512, 2) void fused_kernel(
    const float* __restrict__ nsrc, const float* __restrict__ ndst,
    const float* __restrict__ efeat, const float* __restrict__ lenv,
    const float* __restrict__ escal,
    const __bf16* __restrict__ ws,
    float* __restrict__ out, int E)
{
  __shared__ __align__(16) char lds[49152];
  const int tid = threadIdx.x;
  const int wave = tid >> 6, l = tid & 63;
  const int lg = l >> 4, li = l & 15;
  const int ebase = blockIdx.x * 64;

  char* coeff = lds;
  char* h2n = lds + 32768;
  char* h2e = lds + 40960;

  const int half   = (wave >> 2) & 1;  // q role
  const int rt_role = (wave >> 1) & 1;
  const int eh     = wave & 1;
  const int uh     = half;             // main role reuses bit2
  const int rtw    = rt_role;

  // ---------------- MLP: one 16-e tile per wave ----------------
  {
    const int br = wave >> 2;
    const int ctm = wave & 3;
    const __bf16* M1 = ws + (br ? WS_M1E : WS_M1N);
    const __bf16* M2 = ws + (br ? WS_M2E : WS_M2N);
    char* h2buf = br ? h2e : h2n;
    char* h1s = coeff + wave * 2048;   // private scratch rows hl=li
    int el = ctm * 16 + li;
    int hl = li;
    int ee = min(ebase + el, E - 1);
    bf16x8 bx;
    #pragma unroll
    for (int i = 0; i < 8; ++i) bx[i] = (__bf16)0.f;
    if (lg == 0) {
      const float* xp = escal + (size_t)ee * 8;
      float4 t0 = *(const float4*)(xp);
      float4 t1 = *(const float4*)(xp + 4);
      bx[0]=(__bf16)t0.x; bx[1]=(__bf16)t0.y; bx[2]=(__bf16)t0.z; bx[3]=(__bf16)t0.w;
      bx[4]=(__bf16)t1.x; bx[5]=(__bf16)t1.y; bx[6]=(__bf16)t1.z; bx[7]=(__bf16)t1.w;
    }
    f32x4 hc[4];
    #pragma unroll
    for (int rt = 0; rt < 4; ++rt) {
      bf16x8 a = *(const bf16x8*)(M1 + (rt * 16 + li) * 32 + lg * 8);
      f32x4 c = {0.f, 0.f, 0.f, 0.f};
      hc[rt] = MFMA16(a, bx, c);
    }
    #pragma unroll
    for (int rt = 0; rt < 4; ++rt) {
      int j0 = rt * 16 + lg * 4;
      int g = j0 >> 3;
      int addr = hl * 128 + (((g ^ (hl & 7)) << 4)) + (j0 & 7) * 2;
      uint2 wv; wv.x = pk2(siluf(hc[rt][0]), siluf(hc[rt][1]));
      wv.y = pk2(siluf(hc[rt][2]), siluf(hc[rt][3]));
      *(uint2*)(h1s + addr) = wv;
    }
    f32x4 h2c[4];
    #pragma unroll
    for (int rt = 0; rt < 4; ++rt) { f32x4 z = {0.f,0.f,0.f,0.f}; h2c[rt] = z; }
    #pragma unroll
    for (int kj = 0; kj < 2; ++kj) {
      bf16x8 b = *(const bf16x8*)(h1s + hl * 128 + (((kj * 4 + lg) ^ (hl & 7)) << 4));
      #pragma unroll
      for (int rt = 0; rt < 4; ++rt) {
        bf16x8 a = *(const bf16x8*)(M2 + (rt * 16 + li) * 64 + kj * 32 + lg * 8);
        h2c[rt] = MFMA16(a, b, h2c[rt]);
      }
    }
    #pragma unroll
    for (int rt = 0; rt < 4; ++rt) {
      int j0 = rt * 16 + lg * 4;
      int g = j0 >> 3;
      int addr = el * 128 + (((g ^ (el & 7)) << 4)) + (j0 & 7) * 2;
      uint2 wv; wv.x = pk2(siluf(h2c[rt][0]), siluf(h2c[rt][1]));
      wv.y = pk2(siluf(h2c[rt][2]), siluf(h2c[rt][3]));
      *(uint2*)(h2buf + addr) = wv;
    }
  }
  __syncthreads();   // h1 scratch dead; h2n/h2e ready

  // ---------------- tp coefficient GEMMs -> shared coeff[u][e] ----------------
  auto q_phase = [&](const float* f0, const float* f1, int nk, const __bf16* T, int ustride) {
    #pragma unroll 1
    for (int ct = 0; ct < 2; ++ct) {
      int el = eh * 32 + ct * 16 + li;
      int ee = min(ebase + el, E - 1);
      const float4 le = *(const float4*)(lenv + (size_t)ee * 4);
      const size_t erow = (size_t)ee * 128;
      if (half == 0) {
        f32x4 q1c = {0.f,0.f,0.f,0.f}, q2c = {0.f,0.f,0.f,0.f};
        for (int kj = 0; kj < nk; ++kj) {
          const float* fp = (kj ? f1 : f0) + erow + lg * 8;
          float4 t0 = *(const float4*)(fp);
          float4 t1 = *(const float4*)(fp + 4);
          bf16x8 b;
          b[0]=(__bf16)t0.x; b[1]=(__bf16)t0.y; b[2]=(__bf16)t0.z; b[3]=(__bf16)t0.w;
          b[4]=(__bf16)t1.x; b[5]=(__bf16)t1.y; b[6]=(__bf16)t1.z; b[7]=(__bf16)t1.w;
          bf16x8 a1 = *(const bf16x8*)(T + (rt_role * 16 + li) * ustride + kj * 32 + lg * 8);
          bf16x8 a2 = *(const bf16x8*)(T + 32 * ustride + (rt_role * 16 + li) * ustride + kj * 32 + lg * 8);
          q1c = MFMA16(a1, b, q1c);
          q2c = MFMA16(a2, b, q2c);
        }
        #pragma unroll
        for (int r = 0; r < 4; ++r) {
          uint2 cw;
          cw.x = pk2(q1c[r] * le.x, q2c[r] * le.y);
          cw.y = pk2(q2c[r] * le.z, q2c[r] * le.w);
          *(uint2*)(coeff + (rt_role * 16 + lg * 4 + r) * 512 + el * 8) = cw;
        }
      } else {
        f32x4 q30 = {0.f,0.f,0.f,0.f}, q31 = {0.f,0.f,0.f,0.f}, q32 = {0.f,0.f,0.f,0.f}, q4c = {0.f,0.f,0.f,0.f};
        for (int kj = 0; kj < nk; ++kj) {
          const float* fp = (kj ? f1 : f0) + erow + 32 + lg * 24;
          float v[24];
          #pragma unroll
          for (int q = 0; q < 6; ++q) {
            float4 t = *(const float4*)(fp + q * 4);
            v[q*4] = t.x; v[q*4+1] = t.y; v[q*4+2] = t.z; v[q*4+3] = t.w;
          }
          bf16x8 b0, b1, b2, bd;
          #pragma unroll
          for (int i = 0; i < 8; ++i) {
            b0[i] = (__bf16)v[3*i]; b1[i] = (__bf16)v[3*i+1]; b2[i] = (__bf16)v[3*i+2];
            bd[i] = (__bf16)(v[3*i] * le.y + v[3*i+1] * le.z + v[3*i+2] * le.w);
          }
          bf16x8 a3 = *(const bf16x8*)(T + 2 * 32 * ustride + (rt_role * 16 + li) * ustride + kj * 32 + lg * 8);
          bf16x8 a4 = *(const bf16x8*)(T + 3 * 32 * ustride + (rt_role * 16 + li) * ustride + kj * 32 + lg * 8);
          q30 = MFMA16(a3, b0, q30); q31 = MFMA16(a3, b1, q31); q32 = MFMA16(a3, b2, q32);
          q4c = MFMA16(a4, bd, q4c);
        }
        #pragma unroll
        for (int r = 0; r < 4; ++r) {
          uint2 cw;
          cw.x = pk2(q4c[r], q30[r] * le.x);
          cw.y = pk2(q31[r] * le.x, q32[r] * le.x);
          *(uint2*)(coeff + (32 + rt_role * 16 + lg * 4 + r) * 512 + el * 8) = cw;
        }
      }
    }
  };

  // ---------------- main GEMM + contraction ----------------
  f32x4 aS[2], aV[2][3];

  auto main_phase = [&](const __bf16* W3T, char* h2buf) {
    bf16x8 bb[2][2];
    #pragma unroll
    for (int ct = 0; ct < 2; ++ct)
      #pragma unroll
      for (int kj = 0; kj < 2; ++kj) {
        int el = eh * 32 + ct * 16 + li;
        bb[ct][kj] = *(const bf16x8*)(h2buf + el * 128 + (((kj * 4 + lg) ^ (el & 7)) << 4));
      }
    #pragma unroll 1
    for (int ul = 0; ul < 32; ++ul) {
      int u = uh * 32 + ul;
      const __bf16* ab = W3T + ((size_t)(u * 32 + rtw * 16) + li) * 64 + lg * 8;
      bf16x8 af[2][2];
      #pragma unroll
      for (int gv = 0; gv < 2; ++gv)
        #pragma unroll
        for (int kj = 0; kj < 2; ++kj)
          af[gv][kj] = *(const bf16x8*)(ab + gv * 131072 + kj * 32);
      #pragma unroll
      for (int ct = 0; ct < 2; ++ct) {
        uint2 cf = *(const uint2*)(coeff + u * 512 + (eh * 32 + ct * 16 + li) * 8);
        float ms = bflo(cf.x), m0 = bfhi(cf.x), m1 = bflo(cf.y), m2 = bfhi(cf.y);
        f32x4 c = {0.f,0.f,0.f,0.f};
        c = MFMA16(af[0][0], bb[ct][0], c);
        c = MFMA16(af[0][1], bb[ct][1], c);
        aS[ct] += ms * c;
        f32x4 d = {0.f,0.f,0.f,0.f};
        d = MFMA16(af[1][0], bb[ct][0], d);
        d = MFMA16(af[1][1], bb[ct][1], d);
        aV[ct][0] += m0 * d;
        aV[ct][1] += m1 * d;
        aV[ct][2] += m2 * d;
      }
    }
  };

  #pragma unroll
  for (int ct = 0; ct < 2; ++ct) {
    f32x4 z = {0.f,0.f,0.f,0.f};
    aS[ct] = z; aV[ct][0] = z; aV[ct][1] = z; aV[ct][2] = z;
  }

  // node branch
  q_phase(nsrc, ndst, 2, ws + WS_TN, 64);
  __syncthreads();                       // node coeffs ready
  main_phase(ws + WS_W3N, h2n);
  __syncthreads();                       // everyone done reading node coeffs
  // edge branch
  q_phase(efeat, efeat, 1, ws + WS_TE, 32);
  __syncthreads();                       // edge coeffs ready
  main_phase(ws + WS_W3E, h2e);
  __syncthreads();                       // all mains done; coeff region -> R1

  // ---------------- cross-wave reduction into R1 (f32x4 granules) ----------------
  char* R1 = lds;
  auto rmw = [&](bool add) {
    #pragma unroll
    for (int ct = 0; ct < 2; ++ct) {
      int e = eh * 32 + ct * 16 + li;
      char* ep = R1 + e * 512;
      #pragma unroll
      for (int r4 = 0; r4 < 1; ++r4) {
        f32x4 s = aS[ct];
        int gs = (rtw * 16 + lg * 4) >> 2;     // rtw*4 + lg
        char* p = ep + ((gs ^ (e & 7)) << 4);
        if (add) s += *(const f32x4*)p;
        *(f32x4*)p = s;
        #pragma unroll
        for (int m = 0; m < 3; ++m) {
          f32x4 x = aV[ct][m];
          int gv = 8 + m * 8 + rtw * 4 + lg;
          char* q = ep + ((gv ^ (e & 7)) << 4);
          if (add) x += *(const f32x4*)q;
          *(f32x4*)q = x;
        }
      }
    }
  };
  if (uh == 0) rmw(false);
  __syncthreads();
  if (uh == 1) rmw(true);
  __syncthreads();

  // ---------------- coalesced store (permute [S | V[m][c]] -> [s | v[c][m]]) ----------------
  #pragma unroll
  for (int it = 0; it < 4; ++it) {
    int chunk = it * 512 + tid;        // 2048 float4 chunks = 64 edges * 128 floats
    int e = chunk >> 5, c4 = chunk & 31;
    f32x4 v;
    #pragma unroll
    for (int q = 0; q < 4; ++q) {
      int f = c4 * 4 + q;
      int g, wd;
      if (f < 32) { g = f >> 2; wd = f & 3; }
      else { int t = f - 32; int w = t / 3; int m = t - w * 3; g = 8 + m * 8 + (w >> 2); wd = w & 3; }
      v[q] = *(const float*)(R1 + e * 512 + ((g ^ (e & 7)) << 4) + wd * 4);
    }
    int ge = ebase + e;
    if (ge < E) *(f32x4*)(out + (size_t)ge * 128 + c4 * 4) = v;
  }
}

extern "C" void kernel_launch(void* const* d_in, const int* in_sizes, int n_in,
                              void* d_out, int out_size, void* d_ws, size_t ws_size,
                              hipStream_t stream) {
  const float* nsrc  = (const float*)d_in[0];
  const float* ndst  = (const float*)d_in[1];
  const float* efeat = (const float*)d_in[2];
  const float* lenv  = (const float*)d_in[3];
  const float* escal = (const float*)d_in[4];
  const float* Wn1 = (const float*)d_in[5];
  const float* Wn2 = (const float*)d_in[6];
  const float* Wn3 = (const float*)d_in[7];
  const float* Wn4 = (const float*)d_in[8];
  const float* We1 = (const float*)d_in[9];
  const float* We2 = (const float*)d_in[10];
  const float* We3 = (const float*)d_in[11];
  const float* We4 = (const float*)d_in[12];
  const float* Mn1 = (const float*)d_in[13];
  const float* Mn2 = (const float*)d_in[14];
  const float* Mn3 = (const float*)d_in[15];
  const float* Me1 = (const float*)d_in[16];
  const float* Me2 = (const float*)d_in[17];
  const float* Me3 = (const float*)d_in[18];
  const float* Lns = (const float*)d_in[19];
  const float* Lnv = (const float*)d_in[20];
  const float* Les = (const float*)d_in[21];
  const float* Lev = (const float*)d_in[22];
  (void)n_in; (void)ws_size;

  int E = in_sizes[0] / 128;
  __bf16* ws = (__bf16*)d_ws;
  float* outp = (float*)d_out;
  (void)out_size;

  int nprep = (WS_CNT + 255) / 256;
  hipLaunchKernelGGL(prep_kernel, dim3(nprep), dim3(256), 0, stream,
                     Wn1, Wn2, Wn3, Wn4, We1, We2, We3, We4,
                     Mn1, Mn2, Mn3, Me1, Me2, Me3,
                     Lns, Lnv, Les, Lev, ws);

  int nwg = (E + 63) / 64;
  hipLaunchKernelGGL(fused_kernel, dim3(nwg), dim3(512), 0, stream,
                     nsrc, ndst, efeat, lenv, escal, ws, outp, E);
}

// Round 6
// 150.445 us; speedup vs baseline: 1.0887x; 1.0277x over previous
//
#include <hip/hip_runtime.h>

typedef __attribute__((ext_vector_type(8))) __bf16 bf16x8;
typedef __attribute__((ext_vector_type(4))) float f32x4;

#define MFMA16(A,B,C) __builtin_amdgcn_mfma_f32_16x16x32_bf16(A,B,C,0,0,0)

// ---- ws layout in __bf16 elements ----
#define WS_W3N 0         // [4096][64]  folded node W3 (incl. Lns/Lnv, all scales)
#define WS_W3E 262144    // [4096][64]
#define WS_TN  524288    // [4][32][64] node tp weights^T * alpha
#define WS_TE  532480    // [4][32][32] edge tp weights^T * alpha
#define WS_M1N 536576    // [64][32] (k<8 real, rest 0) * 1/sqrt(8)
#define WS_M2N 538624    // [64][64] * 1/8
#define WS_M1E 542720
#define WS_M2E 544768
#define WS_CNT 548864    // elements (=1097728 bytes)

__global__ void prep_kernel(
    const float* __restrict__ Wn1, const float* __restrict__ Wn2,
    const float* __restrict__ Wn3, const float* __restrict__ Wn4,
    const float* __restrict__ We1, const float* __restrict__ We2,
    const float* __restrict__ We3, const float* __restrict__ We4,
    const float* __restrict__ Mn1, const float* __restrict__ Mn2, const float* __restrict__ Mn3,
    const float* __restrict__ Me1, const float* __restrict__ Me2, const float* __restrict__ Me3,
    const float* __restrict__ Lns, const float* __restrict__ Lnv,
    const float* __restrict__ Les, const float* __restrict__ Lev,
    __bf16* __restrict__ ws)
{
  int idx = blockIdx.x * 256 + threadIdx.x;
  const float c1 = 0.0027621359f;            // 1/(8*8*sqrt(32))
  const float an = 0.125f;                   // node tp alpha (1/sqrt(64))
  const float ae = 0.17677669529663687f;     // edge tp alpha (1/sqrt(32))
  const float r3 = 0.5773502691896258f;      // 1/sqrt(3)
  const float m1s = 0.35355339059327373f;    // 1/sqrt(8)
  const float m2s = 0.125f;                  // 1/sqrt(64)
  if (idx < 524288) {
    int br = idx >> 18;
    int rem = idx & 262143;
    int j = rem >> 12;
    int kc = rem & 4095;
    int vh = kc >> 11;
    int r2 = kc & 2047;
    int u = r2 >> 5, wp = r2 & 31;
    const float* M3 = br ? Me3 : Mn3;
    const float* L  = vh ? (br ? Lev : Lnv) : (br ? Les : Lns);
    const float* mrow = M3 + (size_t)j * 4096 + vh * 2048 + u * 32;
    float s = 0.f;
    #pragma unroll
    for (int w = 0; w < 32; ++w) s += mrow[w] * L[w * 32 + wp];
    ws[(br ? WS_W3E : WS_W3N) + (size_t)kc * 64 + j] = (__bf16)(s * c1);
  } else if (idx < 524288 + 8192) {
    int t = idx - 524288;
    int i = t >> 11; int r = t & 2047; int w = r >> 6; int u = r & 63;
    const float* W = (i == 0) ? Wn1 : (i == 1) ? Wn2 : (i == 2) ? Wn3 : Wn4;
    float sc = an * ((i == 3) ? r3 : 1.f);
    ws[WS_TN + t] = (__bf16)(W[u * 32 + w] * sc);
  } else if (idx < 524288 + 12288) {
    int t = idx - 532480;
    int i = t >> 10; int r = t & 1023; int w = r >> 5; int u = r & 31;
    const float* W = (i == 0) ? We1 : (i == 1) ? We2 : (i == 2) ? We3 : We4;
    float sc = ae * ((i == 3) ? r3 : 1.f);
    ws[WS_TE + t] = (__bf16)(W[u * 32 + w] * sc);
  } else if (idx < 536576 + 2048) {
    int t = idx - 536576;
    int j = t >> 5, k = t & 31;
    ws[WS_M1N + t] = (__bf16)((k < 8) ? Mn1[k * 64 + j] * m1s : 0.f);
  } else if (idx < 538624 + 4096) {
    int t = idx - 538624;
    int j2 = t >> 6, j = t & 63;
    ws[WS_M2N + t] = (__bf16)(Mn2[j * 64 + j2] * m2s);
  } else if (idx < 542720 + 2048) {
    int t = idx - 542720;
    int j = t >> 5, k = t & 31;
    ws[WS_M1E + t] = (__bf16)((k < 8) ? Me1[k * 64 + j] * m1s : 0.f);
  } else if (idx < 544768 + 4096) {
    int t = idx - 544768;
    int j2 = t >> 6, j = t & 63;
    ws[WS_M2E + t] = (__bf16)(Me2[j * 64 + j2] * m2s);
  }
}

__device__ __forceinline__ float siluf(float x) { return x / (1.0f + __expf(-x)); }
__device__ __forceinline__ unsigned int pk2(float lo, float hi) {
  unsigned short a = __builtin_bit_cast(unsigned short, (__bf16)lo);
  unsigned short b = __builtin_bit_cast(unsigned short, (__bf16)hi);
  return (unsigned int)a | ((unsigned int)b << 16);
}
__device__ __forceinline__ float bflo(unsigned int v) { return __builtin_bit_cast(float, (unsigned int)(v << 16)); }
__device__ __forceinline__ float bfhi(unsigned int v) { return __builtin_bit_cast(float, (unsigned int)(v & 0xffff0000u)); }

// 32 edges per WG. LDS map (24576 B / WG):
//   [0,16384)      coeff: wave w at w*4096 : [u_local 16][e 32] * 8B (bf16x4)
//                  (first 2KB of own region doubles as MLP h1 scratch, dead
//                   before q_phase writes coefficients over it)
//   [16384,20480)  h2n  : [e 32][64 j bf16, 16B-granule XOR swizzled]
//   [20480,24576)  h2e
// After mains, [0,16384) becomes the reduction buffer R1
// (32 e x 512B: granule gs=c>>2 holds S[c], gs=8+m*8+(w>>2) holds V[m][w]).
//
// __launch_bounds__(256,3): cap ~170 VGPR so the compiler allocates the
// ~100-130 it needs (no spill); at <=128 VGPR the HW gives 4 waves/SIMD,
// and the 938-WG grid then sustains ~14.7 waves/CU.
__global__ __launch_bounds__(256, 3) void fused_kernel(
    const float* __restrict__ nsrc, const float* __restrict__ ndst,
    const float* __restrict__ efeat, const float* __restrict__ lenv,
    const float* __restrict__ escal,
    const __bf16* __restrict__ ws,
    float* __restrict__ out, int E)
{
  __shared__ __align__(16) char lds[24576];
  const int tid = threadIdx.x;
  const int wave = tid >> 6, l = tid & 63;
  const int lg = l >> 4, li = l & 15;
  const int ebase = blockIdx.x * 32;

  char* coeffw = lds + wave * 4096;
  char* h2n = lds + 16384;
  char* h2e = lds + 20480;

  const int rt_role = wave & 1;   // q-row tile role
  const int half = wave >> 1;     // 0: q1,q2  1: q3,q4

  // ---------------- MLP: wave = (branch<<1) | ct, one e-tile each ----------------
  {
    const int br = wave >> 1;
    const int ct = wave & 1;
    const __bf16* M1 = ws + (br ? WS_M1E : WS_M1N);
    const __bf16* M2 = ws + (br ? WS_M2E : WS_M2N);
    char* h2buf = br ? h2e : h2n;
    char* h1s = coeffw;           // private scratch (hl in [0,16))
    int el = ct * 16 + li;
    int hl = li;
    int ee = min(ebase + el, E - 1);
    bf16x8 bx;
    #pragma unroll
    for (int i = 0; i < 8; ++i) bx[i] = (__bf16)0.f;
    if (lg == 0) {
      const float* xp = escal + (size_t)ee * 8;
      float4 t0 = *(const float4*)(xp);
      float4 t1 = *(const float4*)(xp + 4);
      bx[0]=(__bf16)t0.x; bx[1]=(__bf16)t0.y; bx[2]=(__bf16)t0.z; bx[3]=(__bf16)t0.w;
      bx[4]=(__bf16)t1.x; bx[5]=(__bf16)t1.y; bx[6]=(__bf16)t1.z; bx[7]=(__bf16)t1.w;
    }
    f32x4 hc[4];
    #pragma unroll
    for (int rt = 0; rt < 4; ++rt) {
      bf16x8 a = *(const bf16x8*)(M1 + (rt * 16 + li) * 32 + lg * 8);
      f32x4 c = {0.f, 0.f, 0.f, 0.f};
      hc[rt] = MFMA16(a, bx, c);
    }
    #pragma unroll
    for (int rt = 0; rt < 4; ++rt) {
      int j0 = rt * 16 + lg * 4;
      int g = j0 >> 3;
      int addr = hl * 128 + (((g ^ (hl & 7)) << 4)) + (j0 & 7) * 2;
      uint2 wv; wv.x = pk2(siluf(hc[rt][0]), siluf(hc[rt][1]));
      wv.y = pk2(siluf(hc[rt][2]), siluf(hc[rt][3]));
      *(uint2*)(h1s + addr) = wv;
    }
    f32x4 h2c[4];
    #pragma unroll
    for (int rt = 0; rt < 4; ++rt) { f32x4 z = {0.f,0.f,0.f,0.f}; h2c[rt] = z; }
    #pragma unroll
    for (int kj = 0; kj < 2; ++kj) {
      bf16x8 b = *(const bf16x8*)(h1s + hl * 128 + (((kj * 4 + lg) ^ (hl & 7)) << 4));
      #pragma unroll
      for (int rt = 0; rt < 4; ++rt) {
        bf16x8 a = *(const bf16x8*)(M2 + (rt * 16 + li) * 64 + kj * 32 + lg * 8);
        h2c[rt] = MFMA16(a, b, h2c[rt]);
      }
    }
    #pragma unroll
    for (int rt = 0; rt < 4; ++rt) {
      int j0 = rt * 16 + lg * 4;
      int g = j0 >> 3;
      int addr = el * 128 + (((g ^ (el & 7)) << 4)) + (j0 & 7) * 2;
      uint2 wv; wv.x = pk2(siluf(h2c[rt][0]), siluf(h2c[rt][1]));
      wv.y = pk2(siluf(h2c[rt][2]), siluf(h2c[rt][3]));
      *(uint2*)(h2buf + addr) = wv;
    }
  }

  // ---------------- tp coefficient GEMMs -> coeff LDS ----------------
  auto q_phase = [&](const float* f0, const float* f1, int nk, const __bf16* T, int ustride) {
    for (int ct = 0; ct < 2; ++ct) {
      int el = ct * 16 + li;
      int ee = min(ebase + el, E - 1);
      const float4 le = *(const float4*)(lenv + (size_t)ee * 4);
      const size_t erow = (size_t)ee * 128;
      if (half == 0) {
        f32x4 q1c = {0.f,0.f,0.f,0.f}, q2c = {0.f,0.f,0.f,0.f};
        for (int kj = 0; kj < nk; ++kj) {
          const float* fp = (kj ? f1 : f0) + erow + lg * 8;
          float4 t0 = *(const float4*)(fp);
          float4 t1 = *(const float4*)(fp + 4);
          bf16x8 b;
          b[0]=(__bf16)t0.x; b[1]=(__bf16)t0.y; b[2]=(__bf16)t0.z; b[3]=(__bf16)t0.w;
          b[4]=(__bf16)t1.x; b[5]=(__bf16)t1.y; b[6]=(__bf16)t1.z; b[7]=(__bf16)t1.w;
          bf16x8 a1 = *(const bf16x8*)(T + (rt_role * 16 + li) * ustride + kj * 32 + lg * 8);
          bf16x8 a2 = *(const bf16x8*)(T + 32 * ustride + (rt_role * 16 + li) * ustride + kj * 32 + lg * 8);
          q1c = MFMA16(a1, b, q1c);
          q2c = MFMA16(a2, b, q2c);
        }
        #pragma unroll
        for (int r = 0; r < 4; ++r) {
          uint2 cw;
          cw.x = pk2(q1c[r] * le.x, q2c[r] * le.y);
          cw.y = pk2(q2c[r] * le.z, q2c[r] * le.w);
          *(uint2*)(coeffw + (lg * 4 + r) * 256 + el * 8) = cw;
        }
      } else {
        f32x4 q30 = {0.f,0.f,0.f,0.f}, q31 = {0.f,0.f,0.f,0.f}, q32 = {0.f,0.f,0.f,0.f}, q4c = {0.f,0.f,0.f,0.f};
        for (int kj = 0; kj < nk; ++kj) {
          const float* fp = (kj ? f1 : f0) + erow + 32 + lg * 24;
          float v[24];
          #pragma unroll
          for (int q = 0; q < 6; ++q) {
            float4 t = *(const float4*)(fp + q * 4);
            v[q*4] = t.x; v[q*4+1] = t.y; v[q*4+2] = t.z; v[q*4+3] = t.w;
          }
          bf16x8 b0, b1, b2, bd;
          #pragma unroll
          for (int i = 0; i < 8; ++i) {
            b0[i] = (__bf16)v[3*i]; b1[i] = (__bf16)v[3*i+1]; b2[i] = (__bf16)v[3*i+2];
            bd[i] = (__bf16)(v[3*i] * le.y + v[3*i+1] * le.z + v[3*i+2] * le.w);
          }
          bf16x8 a3 = *(const bf16x8*)(T + 2 * 32 * ustride + (rt_role * 16 + li) * ustride + kj * 32 + lg * 8);
          bf16x8 a4 = *(const bf16x8*)(T + 3 * 32 * ustride + (rt_role * 16 + li) * ustride + kj * 32 + lg * 8);
          q30 = MFMA16(a3, b0, q30); q31 = MFMA16(a3, b1, q31); q32 = MFMA16(a3, b2, q32);
          q4c = MFMA16(a4, bd, q4c);
        }
        #pragma unroll
        for (int r = 0; r < 4; ++r) {
          uint2 cw;
          cw.x = pk2(q4c[r], q30[r] * le.x);
          cw.y = pk2(q31[r] * le.x, q32[r] * le.x);
          *(uint2*)(coeffw + (lg * 4 + r) * 256 + el * 8) = cw;
        }
      }
    }
  };

  // ---------------- main GEMM + contraction ----------------
  f32x4 aS0[2], aV0[2][3], aS1[2], aV1[2][3];

  auto load_af = [&](const __bf16* W3T, int u, int rt, bf16x8 (&af)[2][2]) {
    const __bf16* ab = W3T + ((size_t)(u * 32 + rt * 16) + li) * 64 + lg * 8;
    #pragma unroll
    for (int gv = 0; gv < 2; ++gv)
      #pragma unroll
      for (int kj = 0; kj < 2; ++kj)
        af[gv][kj] = *(const bf16x8*)(ab + gv * 131072 + kj * 32);
  };

  auto compute_ul = [&](const bf16x8 (&af)[2][2], int ul, const bf16x8 (&bb)[2][2],
                        f32x4 (&aS)[2], f32x4 (&aV)[2][3]) {
    #pragma unroll
    for (int ct = 0; ct < 2; ++ct) {
      uint2 cf = *(const uint2*)(coeffw + ul * 256 + (ct * 16 + li) * 8);
      float ms = bflo(cf.x), m0 = bfhi(cf.x), m1 = bflo(cf.y), m2 = bfhi(cf.y);
      f32x4 c = {0.f,0.f,0.f,0.f};
      c = MFMA16(af[0][0], bb[ct][0], c);
      c = MFMA16(af[0][1], bb[ct][1], c);
      aS[ct] += ms * c;
      f32x4 d = {0.f,0.f,0.f,0.f};
      d = MFMA16(af[1][0], bb[ct][0], d);
      d = MFMA16(af[1][1], bb[ct][1], d);
      aV[ct][0] += m0 * d;
      aV[ct][1] += m1 * d;
      aV[ct][2] += m2 * d;
    }
  };

  auto run_pass = [&](const __bf16* W3T, const bf16x8 (&bb)[2][2], int rt,
                      f32x4 (&aS)[2], f32x4 (&aV)[2][3]) {
    const int ubase = wave << 4;
    #pragma unroll 1
    for (int ul = 0; ul < 16; ++ul) {
      bf16x8 af[2][2];
      load_af(W3T, ubase + ul, rt, af);
      compute_ul(af, ul, bb, aS, aV);
    }
  };

  auto main_phase = [&](const __bf16* W3T, char* h2buf) {
    bf16x8 bb[2][2];
    #pragma unroll
    for (int ct = 0; ct < 2; ++ct)
      #pragma unroll
      for (int kj = 0; kj < 2; ++kj) {
        int el = ct * 16 + li;
        bb[ct][kj] = *(const bf16x8*)(h2buf + el * 128 + (((kj * 4 + lg) ^ (el & 7)) << 4));
      }
    run_pass(W3T, bb, 0, aS0, aV0);
    run_pass(W3T, bb, 1, aS1, aV1);
  };

  // node branch
  q_phase(nsrc, ndst, 2, ws + WS_TN, 64);
  __syncthreads();                       // h2n/h2e + all coeffs ready

  #pragma unroll
  for (int ct = 0; ct < 2; ++ct) {
    f32x4 z = {0.f,0.f,0.f,0.f};
    aS0[ct] = z; aV0[ct][0] = z; aV0[ct][1] = z; aV0[ct][2] = z;
    aS1[ct] = z; aV1[ct][0] = z; aV1[ct][1] = z; aV1[ct][2] = z;
  }

  main_phase(ws + WS_W3N, h2n);
  // edge branch (coeff buffer is wave-private; no barrier needed)
  q_phase(efeat, efeat, 1, ws + WS_TE, 32);
  main_phase(ws + WS_W3E, h2e);
  __syncthreads();                       // all mains done; coeff region -> R1

  // ---------------- serial cross-wave reduction into R1 (f32x4 granules) ----------------
  char* R1 = lds;
  auto rmw = [&](bool add) {
    #pragma unroll
    for (int ct = 0; ct < 2; ++ct) {
      int e = ct * 16 + li;
      char* ep = R1 + e * 512;
      #pragma unroll
      for (int rt = 0; rt < 2; ++rt) {
        f32x4 s = rt ? aS1[ct] : aS0[ct];
        int gs = rt * 4 + lg;
        char* p = ep + ((gs ^ (e & 7)) << 4);
        if (add) s += *(const f32x4*)p;
        *(f32x4*)p = s;
        #pragma unroll
        for (int m = 0; m < 3; ++m) {
          f32x4 x = rt ? aV1[ct][m] : aV0[ct][m];
          int gv = 8 + m * 8 + rt * 4 + lg;
          char* q = ep + ((gv ^ (e & 7)) << 4);
          if (add) x += *(const f32x4*)q;
          *(f32x4*)q = x;
        }
      }
    }
  };
  if (wave == 0) rmw(false);
  __syncthreads();
  if (wave == 1) rmw(true);
  __syncthreads();
  if (wave == 2) rmw(true);
  __syncthreads();
  if (wave == 3) rmw(true);
  __syncthreads();

  // ---------------- coalesced store (permute [S | V[m][c]] -> [s | v[c][m]]) ----------------
  #pragma unroll
  for (int it = 0; it < 4; ++it) {
    int chunk = it * 256 + tid;        // 1024 float4 chunks = 32 edges * 128 floats
    int e = chunk >> 5, c4 = chunk & 31;
    f32x4 v;
    #pragma unroll
    for (int q = 0; q < 4; ++q) {
      int f = c4 * 4 + q;
      int g, wd;
      if (f < 32) { g = f >> 2; wd = f & 3; }
      else { int t = f - 32; int w = t / 3; int m = t - w * 3; g = 8 + m * 8 + (w >> 2); wd = w & 3; }
      v[q] = *(const float*)(R1 + e * 512 + ((g ^ (e & 7)) << 4) + wd * 4);
    }
    int ge = ebase + e;
    if (ge < E) *(f32x4*)(out + (size_t)ge * 128 + c4 * 4) = v;
  }
}

extern "C" void kernel_launch(void* const* d_in, const int* in_sizes, int n_in,
                              void* d_out, int out_size, void* d_ws, size_t ws_size,
                              hipStream_t stream) {
  const float* nsrc  = (const float*)d_in[0];
  const float* ndst  = (const float*)d_in[1];
  const float* efeat = (const float*)d_in[2];
  const float* lenv  = (const float*)d_in[3];
  const float* escal = (const float*)d_in[4];
  const float* Wn1 = (const float*)d_in[5];
  const float* Wn2 = (const float*)d_in[6];
  const float* Wn3 = (const float*)d_in[7];
  const float* Wn4 = (const float*)d_in[8];
  const float* We1 = (const float*)d_in[9];
  const float* We2 = (const float*)d_in[10];
  const float* We3 = (const float*)d_in[11];
  const float* We4 = (const float*)d_in[12];
  const float* Mn1 = (const float*)d_in[13];
  const float* Mn2 = (const float*)d_in[14];
  const float* Mn3 = (const float*)d_in[15];
  const float* Me1 = (const float*)d_in[16];
  const float* Me2 = (const float*)d_in[17];
  const float* Me3 = (const float*)d_in[18];
  const float* Lns = (const float*)d_in[19];
  const float* Lnv = (const float*)d_in[20];
  const float* Les = (const float*)d_in[21];
  const float* Lev = (const float*)d_in[22];
  (void)n_in; (void)ws_size;

  int E = in_sizes[0] / 128;
  __bf16* ws = (__bf16*)d_ws;
  float* outp = (float*)d_out;
  (void)out_size;

  int nprep = (WS_CNT + 255) / 256;
  hipLaunchKernelGGL(prep_kernel, dim3(nprep), dim3(256), 0, stream,
                     Wn1, Wn2, Wn3, Wn4, We1, We2, We3, We4,
                     Mn1, Mn2, Mn3, Me1, Me2, Me3,
                     Lns, Lnv, Les, Lev, ws);

  int nwg = (E + 31) / 32;
  hipLaunchKernelGGL(fused_kernel, dim3(nwg), dim3(256), 0, stream,
                     nsrc, ndst, efeat, lenv, escal, ws, outp, E);
}

// Round 7
// 76.587 us; speedup vs baseline: 2.1387x; 1.9644x over previous
//
#include <hip/hip_runtime.h>

typedef __attribute__((ext_vector_type(8))) __bf16 bf16x8;
typedef __attribute__((ext_vector_type(4))) float f32x4;

#define MFMA16(A,B,C) __builtin_amdgcn_mfma_f32_16x16x32_bf16(A,B,C,0,0,0)

typedef const __attribute__((address_space(1))) void* gas_ptr;
typedef __attribute__((address_space(3))) void* las_ptr;

// ---- ws layout in __bf16 elements ----
#define WS_W3N 0         // [4096][64]  folded node W3 (incl. Lns/Lnv, all scales)
#define WS_W3E 262144    // [4096][64]
#define WS_TN  524288    // [4][32][64] node tp weights^T * alpha
#define WS_TE  532480    // [4][32][32] edge tp weights^T * alpha
#define WS_M1N 536576    // [64][32] (k<8 real, rest 0) * 1/sqrt(8)
#define WS_M2N 538624    // [64][64] * 1/8
#define WS_M1E 542720
#define WS_M2E 544768
#define WS_CNT 548864    // elements (=1097728 bytes)

__global__ void prep_kernel(
    const float* __restrict__ Wn1, const float* __restrict__ Wn2,
    const float* __restrict__ Wn3, const float* __restrict__ Wn4,
    const float* __restrict__ We1, const float* __restrict__ We2,
    const float* __restrict__ We3, const float* __restrict__ We4,
    const float* __restrict__ Mn1, const float* __restrict__ Mn2, const float* __restrict__ Mn3,
    const float* __restrict__ Me1, const float* __restrict__ Me2, const float* __restrict__ Me3,
    const float* __restrict__ Lns, const float* __restrict__ Lnv,
    const float* __restrict__ Les, const float* __restrict__ Lev,
    __bf16* __restrict__ ws)
{
  int idx = blockIdx.x * 256 + threadIdx.x;
  const float c1 = 0.0027621359f;            // 1/(8*8*sqrt(32))
  const float an = 0.125f;                   // node tp alpha (1/sqrt(64))
  const float ae = 0.17677669529663687f;     // edge tp alpha (1/sqrt(32))
  const float r3 = 0.5773502691896258f;      // 1/sqrt(3)
  const float m1s = 0.35355339059327373f;    // 1/sqrt(8)
  const float m2s = 0.125f;                  // 1/sqrt(64)
  if (idx < 524288) {
    int br = idx >> 18;
    int rem = idx & 262143;
    int j = rem >> 12;
    int kc = rem & 4095;
    int vh = kc >> 11;
    int r2 = kc & 2047;
    int u = r2 >> 5, wp = r2 & 31;
    const float* M3 = br ? Me3 : Mn3;
    const float* L  = vh ? (br ? Lev : Lnv) : (br ? Les : Lns);
    const float* mrow = M3 + (size_t)j * 4096 + vh * 2048 + u * 32;
    float s = 0.f;
    #pragma unroll
    for (int w = 0; w < 32; ++w) s += mrow[w] * L[w * 32 + wp];
    ws[(br ? WS_W3E : WS_W3N) + (size_t)kc * 64 + j] = (__bf16)(s * c1);
  } else if (idx < 524288 + 8192) {
    int t = idx - 524288;
    int i = t >> 11; int r = t & 2047; int w = r >> 6; int u = r & 63;
    const float* W = (i == 0) ? Wn1 : (i == 1) ? Wn2 : (i == 2) ? Wn3 : Wn4;
    float sc = an * ((i == 3) ? r3 : 1.f);
    ws[WS_TN + t] = (__bf16)(W[u * 32 + w] * sc);
  } else if (idx < 524288 + 12288) {
    int t = idx - 532480;
    int i = t >> 10; int r = t & 1023; int w = r >> 5; int u = r & 31;
    const float* W = (i == 0) ? We1 : (i == 1) ? We2 : (i == 2) ? We3 : We4;
    float sc = ae * ((i == 3) ? r3 : 1.f);
    ws[WS_TE + t] = (__bf16)(W[u * 32 + w] * sc);
  } else if (idx < 536576 + 2048) {
    int t = idx - 536576;
    int j = t >> 5, k = t & 31;
    ws[WS_M1N + t] = (__bf16)((k < 8) ? Mn1[k * 64 + j] * m1s : 0.f);
  } else if (idx < 538624 + 4096) {
    int t = idx - 538624;
    int j2 = t >> 6, j = t & 63;
    ws[WS_M2N + t] = (__bf16)(Mn2[j * 64 + j2] * m2s);
  } else if (idx < 542720 + 2048) {
    int t = idx - 542720;
    int j = t >> 5, k = t & 31;
    ws[WS_M1E + t] = (__bf16)((k < 8) ? Me1[k * 64 + j] * m1s : 0.f);
  } else if (idx < 544768 + 4096) {
    int t = idx - 544768;
    int j2 = t >> 6, j = t & 63;
    ws[WS_M2E + t] = (__bf16)(Me2[j * 64 + j2] * m2s);
  }
}

__device__ __forceinline__ float siluf(float x) { return x / (1.0f + __expf(-x)); }
__device__ __forceinline__ unsigned int pk2(float lo, float hi) {
  unsigned short a = __builtin_bit_cast(unsigned short, (__bf16)lo);
  unsigned short b = __builtin_bit_cast(unsigned short, (__bf16)hi);
  return (unsigned int)a | ((unsigned int)b << 16);
}
__device__ __forceinline__ float bflo(unsigned int v) { return __builtin_bit_cast(float, (unsigned int)(v << 16)); }
__device__ __forceinline__ float bfhi(unsigned int v) { return __builtin_bit_cast(float, (unsigned int)(v & 0xffff0000u)); }

// 64 edges per WG, 256 threads (4 waves). LDS map (81920 B):
//   [0,32768)      coeff[64 u][64 e] * 8B (bf16x4 {ms,m0,m1,m2})
//                  (during MLP: wave*8192 regions hold h1 scratch;
//                   after mains: becomes reduction buffer R1)
//   [32768,40960)  h2n [64 e][128 B, 16B-granule XOR swizzled]
//   [40960,49152)  h2e
//   [49152,81920)  af double buffer: 2 x 16KB. Buffer = [u_idx 2][gv 2] 4KB
//                  chunks; chunk = [row 32][8 granules of 16B, col^(row&7)].
//
// Wave roles: main: uh=wave>>1 (u-half), ep=wave&1 (e-tiles {2ep,2ep+1})
//             q   : half=wave>>1, rt_role=wave&1
//             MLP : br=wave>>1, ctpair=wave&1
// Stage block b holds u={b, 32+b}: every block has work for all 4 waves.
__global__ __launch_bounds__(256, 2) void fused_kernel(
    const float* __restrict__ nsrc, const float* __restrict__ ndst,
    const float* __restrict__ efeat, const float* __restrict__ lenv,
    const float* __restrict__ escal,
    const __bf16* __restrict__ ws,
    float* __restrict__ out, int E)
{
  __shared__ __align__(16) char lds[81920];
  const int tid = threadIdx.x;
  const int wave = tid >> 6, l = tid & 63;
  const int lg = l >> 4, li = l & 15;
  const int ebase = blockIdx.x * 64;

  char* coeff = lds;
  char* h2n = lds + 32768;
  char* h2e = lds + 40960;

  const int uh = wave >> 1;       // main: u-half
  const int ep = wave & 1;        // main: e-pair
  const int half = wave >> 1;     // q role
  const int rt_role = wave & 1;   // q role

  // ---- async stage of af block b (u={b,32+b}) of one branch into buf ----
  auto stage = [&](int buf, int branch, int b) {
    const char* gbase = (const char*)(ws + (branch ? WS_W3E : WS_W3N));
    char* dst = lds + 49152 + buf * 16384 + tid * 16;
    int row = tid >> 3, col = tid & 7;
    int roff = row * 128 + ((col ^ (row & 7)) << 4);   // inverse-swizzled source
    #pragma unroll
    for (int r = 0; r < 4; ++r) {
      int u = b + (r >> 1) * 32, gv = r & 1;
      const char* src = gbase + gv * 262144 + u * 4096 + roff;
      __builtin_amdgcn_global_load_lds((gas_ptr)src, (las_ptr)(dst + r * 4096), 16, 0, 0);
    }
  };

  // ---------------- MLP: wave = (branch, ct-pair), 2 e-tiles each ----------------
  {
    const int br = wave >> 1;
    const __bf16* M1 = ws + (br ? WS_M1E : WS_M1N);
    const __bf16* M2 = ws + (br ? WS_M2E : WS_M2N);
    char* h2buf = br ? h2e : h2n;
    char* h1s = lds + wave * 8192;   // scratch inside coeff region
    #pragma unroll 1
    for (int c2 = 0; c2 < 2; ++c2) {
      int ct = (wave & 1) * 2 + c2;
      int el = ct * 16 + li;
      int hl = c2 * 16 + li;
      int ee = min(ebase + el, E - 1);
      bf16x8 bx;
      #pragma unroll
      for (int i = 0; i < 8; ++i) bx[i] = (__bf16)0.f;
      if (lg == 0) {
        const float* xp = escal + (size_t)ee * 8;
        float4 t0 = *(const float4*)(xp);
        float4 t1 = *(const float4*)(xp + 4);
        bx[0]=(__bf16)t0.x; bx[1]=(__bf16)t0.y; bx[2]=(__bf16)t0.z; bx[3]=(__bf16)t0.w;
        bx[4]=(__bf16)t1.x; bx[5]=(__bf16)t1.y; bx[6]=(__bf16)t1.z; bx[7]=(__bf16)t1.w;
      }
      f32x4 hc[4];
      #pragma unroll
      for (int rt = 0; rt < 4; ++rt) {
        bf16x8 a = *(const bf16x8*)(M1 + (rt * 16 + li) * 32 + lg * 8);
        f32x4 c = {0.f, 0.f, 0.f, 0.f};
        hc[rt] = MFMA16(a, bx, c);
      }
      #pragma unroll
      for (int rt = 0; rt < 4; ++rt) {
        int j0 = rt * 16 + lg * 4;
        int g = j0 >> 3;
        int addr = hl * 128 + (((g ^ (hl & 7)) << 4)) + (j0 & 7) * 2;
        uint2 wv; wv.x = pk2(siluf(hc[rt][0]), siluf(hc[rt][1]));
        wv.y = pk2(siluf(hc[rt][2]), siluf(hc[rt][3]));
        *(uint2*)(h1s + addr) = wv;
      }
      f32x4 h2c[4];
      #pragma unroll
      for (int rt = 0; rt < 4; ++rt) { f32x4 z = {0.f,0.f,0.f,0.f}; h2c[rt] = z; }
      #pragma unroll
      for (int kj = 0; kj < 2; ++kj) {
        bf16x8 b = *(const bf16x8*)(h1s + hl * 128 + (((kj * 4 + lg) ^ (hl & 7)) << 4));
        #pragma unroll
        for (int rt = 0; rt < 4; ++rt) {
          bf16x8 a = *(const bf16x8*)(M2 + (rt * 16 + li) * 64 + kj * 32 + lg * 8);
          h2c[rt] = MFMA16(a, b, h2c[rt]);
        }
      }
      #pragma unroll
      for (int rt = 0; rt < 4; ++rt) {
        int j0 = rt * 16 + lg * 4;
        int g = j0 >> 3;
        int addr = el * 128 + (((g ^ (el & 7)) << 4)) + (j0 & 7) * 2;
        uint2 wv; wv.x = pk2(siluf(h2c[rt][0]), siluf(h2c[rt][1]));
        wv.y = pk2(siluf(h2c[rt][2]), siluf(h2c[rt][3]));
        *(uint2*)(h2buf + addr) = wv;
      }
    }
  }
  __syncthreads();   // h1 scratch dead; h2n/h2e ready; coeff region free

  // ---------------- tp coefficient GEMMs -> shared coeff[u][e] ----------------
  auto q_phase = [&](const float* f0, const float* f1, int nk, const __bf16* T, int ustride) {
    #pragma unroll 1
    for (int ct = 0; ct < 4; ++ct) {
      int el = ct * 16 + li;
      int ee = min(ebase + el, E - 1);
      const float4 le = *(const float4*)(lenv + (size_t)ee * 4);
      const size_t erow = (size_t)ee * 128;
      if (half == 0) {
        f32x4 q1c = {0.f,0.f,0.f,0.f}, q2c = {0.f,0.f,0.f,0.f};
        for (int kj = 0; kj < nk; ++kj) {
          const float* fp = (kj ? f1 : f0) + erow + lg * 8;
          float4 t0 = *(const float4*)(fp);
          float4 t1 = *(const float4*)(fp + 4);
          bf16x8 b;
          b[0]=(__bf16)t0.x; b[1]=(__bf16)t0.y; b[2]=(__bf16)t0.z; b[3]=(__bf16)t0.w;
          b[4]=(__bf16)t1.x; b[5]=(__bf16)t1.y; b[6]=(__bf16)t1.z; b[7]=(__bf16)t1.w;
          bf16x8 a1 = *(const bf16x8*)(T + (rt_role * 16 + li) * ustride + kj * 32 + lg * 8);
          bf16x8 a2 = *(const bf16x8*)(T + 32 * ustride + (rt_role * 16 + li) * ustride + kj * 32 + lg * 8);
          q1c = MFMA16(a1, b, q1c);
          q2c = MFMA16(a2, b, q2c);
        }
        #pragma unroll
        for (int r = 0; r < 4; ++r) {
          uint2 cw;
          cw.x = pk2(q1c[r] * le.x, q2c[r] * le.y);
          cw.y = pk2(q2c[r] * le.z, q2c[r] * le.w);
          *(uint2*)(coeff + (rt_role * 16 + lg * 4 + r) * 512 + el * 8) = cw;
        }
      } else {
        f32x4 q30 = {0.f,0.f,0.f,0.f}, q31 = {0.f,0.f,0.f,0.f}, q32 = {0.f,0.f,0.f,0.f}, q4c = {0.f,0.f,0.f,0.f};
        for (int kj = 0; kj < nk; ++kj) {
          const float* fp = (kj ? f1 : f0) + erow + 32 + lg * 24;
          float v[24];
          #pragma unroll
          for (int q = 0; q < 6; ++q) {
            float4 t = *(const float4*)(fp + q * 4);
            v[q*4] = t.x; v[q*4+1] = t.y; v[q*4+2] = t.z; v[q*4+3] = t.w;
          }
          bf16x8 b0, b1, b2, bd;
          #pragma unroll
          for (int i = 0; i < 8; ++i) {
            b0[i] = (__bf16)v[3*i]; b1[i] = (__bf16)v[3*i+1]; b2[i] = (__bf16)v[3*i+2];
            bd[i] = (__bf16)(v[3*i] * le.y + v[3*i+1] * le.z + v[3*i+2] * le.w);
          }
          bf16x8 a3 = *(const bf16x8*)(T + 2 * 32 * ustride + (rt_role * 16 + li) * ustride + kj * 32 + lg * 8);
          bf16x8 a4 = *(const bf16x8*)(T + 3 * 32 * ustride + (rt_role * 16 + li) * ustride + kj * 32 + lg * 8);
          q30 = MFMA16(a3, b0, q30); q31 = MFMA16(a3, b1, q31); q32 = MFMA16(a3, b2, q32);
          q4c = MFMA16(a4, bd, q4c);
        }
        #pragma unroll
        for (int r = 0; r < 4; ++r) {
          uint2 cw;
          cw.x = pk2(q4c[r], q30[r] * le.x);
          cw.y = pk2(q31[r] * le.x, q32[r] * le.x);
          *(uint2*)(coeff + (32 + rt_role * 16 + lg * 4 + r) * 512 + el * 8) = cw;
        }
      }
    }
  };

  // ---------------- main: LDS-staged af, per-wave (uh, ep) ----------------
  f32x4 aS[2][2], aV[2][2][3];           // [t2][rt], [t2][rt][m]
  #pragma unroll
  for (int t2 = 0; t2 < 2; ++t2)
    #pragma unroll
    for (int rt = 0; rt < 2; ++rt) {
      f32x4 z = {0.f,0.f,0.f,0.f};
      aS[t2][rt] = z;
      aV[t2][rt][0] = z; aV[t2][rt][1] = z; aV[t2][rt][2] = z;
    }

  bf16x8 bb[2][2];
  auto load_bb = [&](char* h2buf) {
    #pragma unroll
    for (int t2 = 0; t2 < 2; ++t2)
      #pragma unroll
      for (int kj = 0; kj < 2; ++kj) {
        int el = (ep * 2 + t2) * 16 + li;
        bb[t2][kj] = *(const bf16x8*)(h2buf + el * 128 + (((kj * 4 + lg) ^ (el & 7)) << 4));
      }
  };

  auto main_block = [&](int buf, int b) {
    const char* afb = lds + 49152 + buf * 16384 + uh * 8192;
    int u_rel = uh * 32 + b;
    uint2 cf0 = *(const uint2*)(coeff + u_rel * 512 + ((ep * 2) * 16 + li) * 8);
    uint2 cf1 = *(const uint2*)(coeff + u_rel * 512 + ((ep * 2 + 1) * 16 + li) * 8);
    bf16x8 afS[2][2], afV[2][2];         // [rt][kj]
    #pragma unroll
    for (int rt = 0; rt < 2; ++rt)
      #pragma unroll
      for (int kj = 0; kj < 2; ++kj) {
        int off = (rt * 16 + li) * 128 + (((kj * 4 + lg) ^ (li & 7)) << 4);
        afS[rt][kj] = *(const bf16x8*)(afb + off);
        afV[rt][kj] = *(const bf16x8*)(afb + 4096 + off);
      }
    #pragma unroll
    for (int t2 = 0; t2 < 2; ++t2) {
      uint2 cf = t2 ? cf1 : cf0;
      float ms = bflo(cf.x), m0 = bfhi(cf.x), m1 = bflo(cf.y), m2 = bfhi(cf.y);
      #pragma unroll
      for (int rt = 0; rt < 2; ++rt) {
        f32x4 c = {0.f,0.f,0.f,0.f};
        c = MFMA16(afS[rt][0], bb[t2][0], c);
        c = MFMA16(afS[rt][1], bb[t2][1], c);
        aS[t2][rt] += ms * c;
        f32x4 d = {0.f,0.f,0.f,0.f};
        d = MFMA16(afV[rt][0], bb[t2][0], d);
        d = MFMA16(afV[rt][1], bb[t2][1], d);
        aV[t2][rt][0] += m0 * d;
        aV[t2][rt][1] += m1 * d;
        aV[t2][rt][2] += m2 * d;
      }
    }
  };

  // node branch: prefetch block0, compute coeffs, then pipelined main loop
  stage(0, 0, 0);
  q_phase(nsrc, ndst, 2, ws + WS_TN, 64);
  __syncthreads();                 // coeff(node) visible + stage0 drained (vmcnt 0)

  load_bb(h2n);
  #pragma unroll 1
  for (int b = 0; b < 32; ++b) {
    if (b < 31) stage((b + 1) & 1, 0, b + 1);
    else        stage(0, 1, 0);    // cross-branch prefetch: edge block0 -> buf0
    main_block(b & 1, b);
    __syncthreads();               // drains stage, releases buffers & coeff
  }

  // edge branch
  q_phase(efeat, efeat, 1, ws + WS_TE, 32);
  __syncthreads();                 // coeff(edge) visible; edge block0 staged

  load_bb(h2e);
  #pragma unroll 1
  for (int b = 0; b < 32; ++b) {
    if (b < 31) stage((b + 1) & 1, 1, b + 1);
    main_block(b & 1, b);
    __syncthreads();
  }

  // ---------------- cross-wave reduction into R1 (= coeff region) ----------------
  char* R1 = lds;
  auto rmw = [&](bool add) {
    #pragma unroll
    for (int t2 = 0; t2 < 2; ++t2) {
      int e = (ep * 2 + t2) * 16 + li;
      char* epp = R1 + e * 512;
      #pragma unroll
      for (int rt = 0; rt < 2; ++rt) {
        f32x4 s = aS[t2][rt];
        char* p = epp + (((rt * 4 + lg) ^ (e & 7)) << 4);
        if (add) s += *(const f32x4*)p;
        *(f32x4*)p = s;
        #pragma unroll
        for (int m = 0; m < 3; ++m) {
          f32x4 x = aV[t2][rt][m];
          char* q = epp + (((8 + m * 8 + rt * 4 + lg) ^ (e & 7)) << 4);
          if (add) x += *(const f32x4*)q;
          *(f32x4*)q = x;
        }
      }
    }
  };
  if (uh == 0) rmw(false);
  __syncthreads();
  if (uh == 1) rmw(true);
  __syncthreads();

  // ---------------- coalesced store (permute [S | V[m][w]] -> [s | v[w][m]]) ----------------
  #pragma unroll
  for (int it = 0; it < 8; ++it) {
    int chunk = it * 256 + tid;        // 2048 float4 chunks = 64 edges * 128 floats
    int e = chunk >> 5, c4 = chunk & 31;
    f32x4 v;
    #pragma unroll
    for (int q = 0; q < 4; ++q) {
      int f = c4 * 4 + q;
      int g, wd;
      if (f < 32) { g = f >> 2; wd = f & 3; }
      else { int t = f - 32; int w = t / 3; int m = t - w * 3; g = 8 + m * 8 + (w >> 2); wd = w & 3; }
      v[q] = *(const float*)(R1 + e * 512 + ((g ^ (e & 7)) << 4) + wd * 4);
    }
    int ge = ebase + e;
    if (ge < E) *(f32x4*)(out + (size_t)ge * 128 + c4 * 4) = v;
  }
}

extern "C" void kernel_launch(void* const* d_in, const int* in_sizes, int n_in,
                              void* d_out, int out_size, void* d_ws, size_t ws_size,
                              hipStream_t stream) {
  const float* nsrc  = (const float*)d_in[0];
  const float* ndst  = (const float*)d_in[1];
  const float* efeat = (const float*)d_in[2];
  const float* lenv  = (const float*)d_in[3];
  const float* escal = (const float*)d_in[4];
  const float* Wn1 = (const float*)d_in[5];
  const float* Wn2 = (const float*)d_in[6];
  const float* Wn3 = (const float*)d_in[7];
  const float* Wn4 = (const float*)d_in[8];
  const float* We1 = (const float*)d_in[9];
  const float* We2 = (const float*)d_in[10];
  const float* We3 = (const float*)d_in[11];
  const float* We4 = (const float*)d_in[12];
  const float* Mn1 = (const float*)d_in[13];
  const float* Mn2 = (const float*)d_in[14];
  const float* Mn3 = (const float*)d_in[15];
  const float* Me1 = (const float*)d_in[16];
  const float* Me2 = (const float*)d_in[17];
  const float* Me3 = (const float*)d_in[18];
  const float* Lns = (const float*)d_in[19];
  const float* Lnv = (const float*)d_in[20];
  const float* Les = (const float*)d_in[21];
  const float* Lev = (const float*)d_in[22];
  (void)n_in; (void)ws_size;

  int E = in_sizes[0] / 128;
  __bf16* ws = (__bf16*)d_ws;
  float* outp = (float*)d_out;
  (void)out_size;

  int nprep = (WS_CNT + 255) / 256;
  hipLaunchKernelGGL(prep_kernel, dim3(nprep), dim3(256), 0, stream,
                     Wn1, Wn2, Wn3, Wn4, We1, We2, We3, We4,
                     Mn1, Mn2, Mn3, Me1, Me2, Me3,
                     Lns, Lnv, Les, Lev, ws);

  int nwg = (E + 63) / 64;
  hipLaunchKernelGGL(fused_kernel, dim3(nwg), dim3(256), 0, stream,
                     nsrc, ndst, efeat, lenv, escal, ws, outp, E);
}

// Round 8
// 72.876 us; speedup vs baseline: 2.2475x; 1.0509x over previous
//
#include <hip/hip_runtime.h>

typedef __attribute__((ext_vector_type(8))) __bf16 bf16x8;
typedef __attribute__((ext_vector_type(4))) float f32x4;

#define MFMA16(A,B,C) __builtin_amdgcn_mfma_f32_16x16x32_bf16(A,B,C,0,0,0)

typedef const __attribute__((address_space(1))) void* gas_ptr;
typedef __attribute__((address_space(3))) void* las_ptr;

// compiler-visible memory fence around raw barrier / counted waitcnt
#define BARRIER() do { asm volatile("" ::: "memory"); __builtin_amdgcn_s_barrier(); asm volatile("" ::: "memory"); } while (0)
#define WAIT_VM4() asm volatile("s_waitcnt vmcnt(4)" ::: "memory")

// ---- ws layout in __bf16 elements ----
#define WS_W3N 0         // [4096][64]  folded node W3 (incl. Lns/Lnv, all scales)
#define WS_W3E 262144    // [4096][64]
#define WS_TN  524288    // [4][32][64] node tp weights^T * alpha
#define WS_TE  532480    // [4][32][32] edge tp weights^T * alpha
#define WS_M1N 536576    // [64][32] (k<8 real, rest 0) * 1/sqrt(8)
#define WS_M2N 538624    // [64][64] * 1/8
#define WS_M1E 542720
#define WS_M2E 544768
#define WS_CNT 548864    // elements (=1097728 bytes)

__global__ void prep_kernel(
    const float* __restrict__ Wn1, const float* __restrict__ Wn2,
    const float* __restrict__ Wn3, const float* __restrict__ Wn4,
    const float* __restrict__ We1, const float* __restrict__ We2,
    const float* __restrict__ We3, const float* __restrict__ We4,
    const float* __restrict__ Mn1, const float* __restrict__ Mn2, const float* __restrict__ Mn3,
    const float* __restrict__ Me1, const float* __restrict__ Me2, const float* __restrict__ Me3,
    const float* __restrict__ Lns, const float* __restrict__ Lnv,
    const float* __restrict__ Les, const float* __restrict__ Lev,
    __bf16* __restrict__ ws)
{
  int idx = blockIdx.x * 256 + threadIdx.x;
  const float c1 = 0.0027621359f;            // 1/(8*8*sqrt(32))
  const float an = 0.125f;                   // node tp alpha (1/sqrt(64))
  const float ae = 0.17677669529663687f;     // edge tp alpha (1/sqrt(32))
  const float r3 = 0.5773502691896258f;      // 1/sqrt(3)
  const float m1s = 0.35355339059327373f;    // 1/sqrt(8)
  const float m2s = 0.125f;                  // 1/sqrt(64)
  if (idx < 524288) {
    int br = idx >> 18;
    int rem = idx & 262143;
    int j = rem >> 12;
    int kc = rem & 4095;
    int vh = kc >> 11;
    int r2 = kc & 2047;
    int u = r2 >> 5, wp = r2 & 31;
    const float* M3 = br ? Me3 : Mn3;
    const float* L  = vh ? (br ? Lev : Lnv) : (br ? Les : Lns);
    const float* mrow = M3 + (size_t)j * 4096 + vh * 2048 + u * 32;
    float s = 0.f;
    #pragma unroll
    for (int w = 0; w < 32; ++w) s += mrow[w] * L[w * 32 + wp];
    ws[(br ? WS_W3E : WS_W3N) + (size_t)kc * 64 + j] = (__bf16)(s * c1);
  } else if (idx < 524288 + 8192) {
    int t = idx - 524288;
    int i = t >> 11; int r = t & 2047; int w = r >> 6; int u = r & 63;
    const float* W = (i == 0) ? Wn1 : (i == 1) ? Wn2 : (i == 2) ? Wn3 : Wn4;
    float sc = an * ((i == 3) ? r3 : 1.f);
    ws[WS_TN + t] = (__bf16)(W[u * 32 + w] * sc);
  } else if (idx < 524288 + 12288) {
    int t = idx - 532480;
    int i = t >> 10; int r = t & 1023; int w = r >> 5; int u = r & 31;
    const float* W = (i == 0) ? We1 : (i == 1) ? We2 : (i == 2) ? We3 : We4;
    float sc = ae * ((i == 3) ? r3 : 1.f);
    ws[WS_TE + t] = (__bf16)(W[u * 32 + w] * sc);
  } else if (idx < 536576 + 2048) {
    int t = idx - 536576;
    int j = t >> 5, k = t & 31;
    ws[WS_M1N + t] = (__bf16)((k < 8) ? Mn1[k * 64 + j] * m1s : 0.f);
  } else if (idx < 538624 + 4096) {
    int t = idx - 538624;
    int j2 = t >> 6, j = t & 63;
    ws[WS_M2N + t] = (__bf16)(Mn2[j * 64 + j2] * m2s);
  } else if (idx < 542720 + 2048) {
    int t = idx - 542720;
    int j = t >> 5, k = t & 31;
    ws[WS_M1E + t] = (__bf16)((k < 8) ? Me1[k * 64 + j] * m1s : 0.f);
  } else if (idx < 544768 + 4096) {
    int t = idx - 544768;
    int j2 = t >> 6, j = t & 63;
    ws[WS_M2E + t] = (__bf16)(Me2[j * 64 + j2] * m2s);
  }
}

__device__ __forceinline__ float siluf(float x) { return x / (1.0f + __expf(-x)); }
__device__ __forceinline__ unsigned int pk2(float lo, float hi) {
  unsigned short a = __builtin_bit_cast(unsigned short, (__bf16)lo);
  unsigned short b = __builtin_bit_cast(unsigned short, (__bf16)hi);
  return (unsigned int)a | ((unsigned int)b << 16);
}
__device__ __forceinline__ float bflo(unsigned int v) { return __builtin_bit_cast(float, (unsigned int)(v << 16)); }
__device__ __forceinline__ float bfhi(unsigned int v) { return __builtin_bit_cast(float, (unsigned int)(v & 0xffff0000u)); }

// 64 edges per WG, 256 threads (4 waves). LDS map (65536 B):
//   [0,32768)      coeff[64 u][64 e] * 8B (bf16x4 {ms,m0,m1,m2})
//                  (during MLP: wave*8192 regions = h1 scratch;
//                   after mains: reduction buffer R1)
//   [32768,65536)  af double buffer: 2 x 16KB, [u_idx 2][gv 2] 4KB chunks;
//                  chunk = [row 32][8 x 16B granules, col^(row&7)].
//                  (during MLP: h2n at +0, h2e at +8192; hoisted to
//                   registers bbN/bbE before staging overwrites.)
//
// Main-loop schedule (T4 counted-vmcnt, invariant: at iter-b entry the
// ONLY in-flight stage is block b+1):
//   compute(b) from buf[b&1]; BARRIER (all done reading);
//   stage(b+2 -> buf[b&1]);   WAIT vmcnt(4) (b+1 landed); BARRIER.
// Never vmcnt(0) inside the loop.
__global__ __launch_bounds__(256, 2) void fused_kernel(
    const float* __restrict__ nsrc, const float* __restrict__ ndst,
    const float* __restrict__ efeat, const float* __restrict__ lenv,
    const float* __restrict__ escal,
    const __bf16* __restrict__ ws,
    float* __restrict__ out, int E)
{
  __shared__ __align__(16) char lds[65536];
  const int tid = threadIdx.x;
  const int wave = tid >> 6, l = tid & 63;
  const int lg = l >> 4, li = l & 15;
  const int ebase = blockIdx.x * 64;

  char* coeff = lds;
  char* afbase = lds + 32768;
  char* h2n = afbase;            // transient (pre-staging)
  char* h2e = afbase + 8192;

  const int uh = wave >> 1;       // main: u-half
  const int ep = wave & 1;        // main: e-pair
  const int half = wave >> 1;     // q role
  const int rt_role = wave & 1;   // q role

  // ---- async stage of af block b (u={b,32+b}) of one branch into buf ----
  auto stage = [&](int buf, int branch, int b) {
    const char* gbase = (const char*)(ws + (branch ? WS_W3E : WS_W3N));
    char* dst = afbase + buf * 16384 + tid * 16;
    int row = tid >> 3, col = tid & 7;
    int roff = row * 128 + ((col ^ (row & 7)) << 4);   // inverse-swizzled source
    #pragma unroll
    for (int r = 0; r < 4; ++r) {
      int u = b + (r >> 1) * 32, gv = r & 1;
      const char* src = gbase + gv * 262144 + u * 4096 + roff;
      __builtin_amdgcn_global_load_lds((gas_ptr)src, (las_ptr)(dst + r * 4096), 16, 0, 0);
    }
  };

  // ---------------- MLP: wave = (branch, ct-pair), 2 e-tiles each ----------------
  {
    const int br = wave >> 1;
    const __bf16* M1 = ws + (br ? WS_M1E : WS_M1N);
    const __bf16* M2 = ws + (br ? WS_M2E : WS_M2N);
    char* h2buf = br ? h2e : h2n;
    char* h1s = lds + wave * 8192;   // scratch inside coeff region
    #pragma unroll 1
    for (int c2 = 0; c2 < 2; ++c2) {
      int ct = (wave & 1) * 2 + c2;
      int el = ct * 16 + li;
      int hl = c2 * 16 + li;
      int ee = min(ebase + el, E - 1);
      bf16x8 bx;
      #pragma unroll
      for (int i = 0; i < 8; ++i) bx[i] = (__bf16)0.f;
      if (lg == 0) {
        const float* xp = escal + (size_t)ee * 8;
        float4 t0 = *(const float4*)(xp);
        float4 t1 = *(const float4*)(xp + 4);
        bx[0]=(__bf16)t0.x; bx[1]=(__bf16)t0.y; bx[2]=(__bf16)t0.z; bx[3]=(__bf16)t0.w;
        bx[4]=(__bf16)t1.x; bx[5]=(__bf16)t1.y; bx[6]=(__bf16)t1.z; bx[7]=(__bf16)t1.w;
      }
      f32x4 hc[4];
      #pragma unroll
      for (int rt = 0; rt < 4; ++rt) {
        bf16x8 a = *(const bf16x8*)(M1 + (rt * 16 + li) * 32 + lg * 8);
        f32x4 c = {0.f, 0.f, 0.f, 0.f};
        hc[rt] = MFMA16(a, bx, c);
      }
      #pragma unroll
      for (int rt = 0; rt < 4; ++rt) {
        int j0 = rt * 16 + lg * 4;
        int g = j0 >> 3;
        int addr = hl * 128 + (((g ^ (hl & 7)) << 4)) + (j0 & 7) * 2;
        uint2 wv; wv.x = pk2(siluf(hc[rt][0]), siluf(hc[rt][1]));
        wv.y = pk2(siluf(hc[rt][2]), siluf(hc[rt][3]));
        *(uint2*)(h1s + addr) = wv;
      }
      f32x4 h2c[4];
      #pragma unroll
      for (int rt = 0; rt < 4; ++rt) { f32x4 z = {0.f,0.f,0.f,0.f}; h2c[rt] = z; }
      #pragma unroll
      for (int kj = 0; kj < 2; ++kj) {
        bf16x8 b = *(const bf16x8*)(h1s + hl * 128 + (((kj * 4 + lg) ^ (hl & 7)) << 4));
        #pragma unroll
        for (int rt = 0; rt < 4; ++rt) {
          bf16x8 a = *(const bf16x8*)(M2 + (rt * 16 + li) * 64 + kj * 32 + lg * 8);
          h2c[rt] = MFMA16(a, b, h2c[rt]);
        }
      }
      #pragma unroll
      for (int rt = 0; rt < 4; ++rt) {
        int j0 = rt * 16 + lg * 4;
        int g = j0 >> 3;
        int addr = el * 128 + (((g ^ (el & 7)) << 4)) + (j0 & 7) * 2;
        uint2 wv; wv.x = pk2(siluf(h2c[rt][0]), siluf(h2c[rt][1]));
        wv.y = pk2(siluf(h2c[rt][2]), siluf(h2c[rt][3]));
        *(uint2*)(h2buf + addr) = wv;
      }
    }
  }
  __syncthreads();   // h2n/h2e ready in af region

  // ---- hoist bb for BOTH branches to registers; af region then freed ----
  bf16x8 bbN[2][2], bbE[2][2];
  #pragma unroll
  for (int t2 = 0; t2 < 2; ++t2)
    #pragma unroll
    for (int kj = 0; kj < 2; ++kj) {
      int el = (ep * 2 + t2) * 16 + li;
      int off = el * 128 + (((kj * 4 + lg) ^ (el & 7)) << 4);
      bbN[t2][kj] = *(const bf16x8*)(h2n + off);
      bbE[t2][kj] = *(const bf16x8*)(h2e + off);
    }
  __syncthreads();   // all bb reads done; staging may overwrite af region

  // ---------------- tp coefficient GEMMs -> shared coeff[u][e] ----------------
  auto q_phase = [&](const float* f0, const float* f1, int nk, const __bf16* T, int ustride) {
    #pragma unroll 1
    for (int ct = 0; ct < 4; ++ct) {
      int el = ct * 16 + li;
      int ee = min(ebase + el, E - 1);
      const float4 le = *(const float4*)(lenv + (size_t)ee * 4);
      const size_t erow = (size_t)ee * 128;
      if (half == 0) {
        f32x4 q1c = {0.f,0.f,0.f,0.f}, q2c = {0.f,0.f,0.f,0.f};
        for (int kj = 0; kj < nk; ++kj) {
          const float* fp = (kj ? f1 : f0) + erow + lg * 8;
          float4 t0 = *(const float4*)(fp);
          float4 t1 = *(const float4*)(fp + 4);
          bf16x8 b;
          b[0]=(__bf16)t0.x; b[1]=(__bf16)t0.y; b[2]=(__bf16)t0.z; b[3]=(__bf16)t0.w;
          b[4]=(__bf16)t1.x; b[5]=(__bf16)t1.y; b[6]=(__bf16)t1.z; b[7]=(__bf16)t1.w;
          bf16x8 a1 = *(const bf16x8*)(T + (rt_role * 16 + li) * ustride + kj * 32 + lg * 8);
          bf16x8 a2 = *(const bf16x8*)(T + 32 * ustride + (rt_role * 16 + li) * ustride + kj * 32 + lg * 8);
          q1c = MFMA16(a1, b, q1c);
          q2c = MFMA16(a2, b, q2c);
        }
        #pragma unroll
        for (int r = 0; r < 4; ++r) {
          uint2 cw;
          cw.x = pk2(q1c[r] * le.x, q2c[r] * le.y);
          cw.y = pk2(q2c[r] * le.z, q2c[r] * le.w);
          *(uint2*)(coeff + (rt_role * 16 + lg * 4 + r) * 512 + el * 8) = cw;
        }
      } else {
        f32x4 q30 = {0.f,0.f,0.f,0.f}, q31 = {0.f,0.f,0.f,0.f}, q32 = {0.f,0.f,0.f,0.f}, q4c = {0.f,0.f,0.f,0.f};
        for (int kj = 0; kj < nk; ++kj) {
          const float* fp = (kj ? f1 : f0) + erow + 32 + lg * 24;
          float v[24];
          #pragma unroll
          for (int q = 0; q < 6; ++q) {
            float4 t = *(const float4*)(fp + q * 4);
            v[q*4] = t.x; v[q*4+1] = t.y; v[q*4+2] = t.z; v[q*4+3] = t.w;
          }
          bf16x8 b0, b1, b2, bd;
          #pragma unroll
          for (int i = 0; i < 8; ++i) {
            b0[i] = (__bf16)v[3*i]; b1[i] = (__bf16)v[3*i+1]; b2[i] = (__bf16)v[3*i+2];
            bd[i] = (__bf16)(v[3*i] * le.y + v[3*i+1] * le.z + v[3*i+2] * le.w);
          }
          bf16x8 a3 = *(const bf16x8*)(T + 2 * 32 * ustride + (rt_role * 16 + li) * ustride + kj * 32 + lg * 8);
          bf16x8 a4 = *(const bf16x8*)(T + 3 * 32 * ustride + (rt_role * 16 + li) * ustride + kj * 32 + lg * 8);
          q30 = MFMA16(a3, b0, q30); q31 = MFMA16(a3, b1, q31); q32 = MFMA16(a3, b2, q32);
          q4c = MFMA16(a4, bd, q4c);
        }
        #pragma unroll
        for (int r = 0; r < 4; ++r) {
          uint2 cw;
          cw.x = pk2(q4c[r], q30[r] * le.x);
          cw.y = pk2(q31[r] * le.x, q32[r] * le.x);
          *(uint2*)(coeff + (32 + rt_role * 16 + lg * 4 + r) * 512 + el * 8) = cw;
        }
      }
    }
  };

  // ---------------- main: LDS-staged af, per-wave (uh, ep) ----------------
  f32x4 aS[2][2], aV[2][2][3];           // [t2][rt], [t2][rt][m]
  #pragma unroll
  for (int t2 = 0; t2 < 2; ++t2)
    #pragma unroll
    for (int rt = 0; rt < 2; ++rt) {
      f32x4 z = {0.f,0.f,0.f,0.f};
      aS[t2][rt] = z;
      aV[t2][rt][0] = z; aV[t2][rt][1] = z; aV[t2][rt][2] = z;
    }

  auto main_block = [&](int buf, int b, const bf16x8 (&bb)[2][2]) {
    const char* afb = afbase + buf * 16384 + uh * 8192;
    int u_rel = uh * 32 + b;
    uint2 cf0 = *(const uint2*)(coeff + u_rel * 512 + ((ep * 2) * 16 + li) * 8);
    uint2 cf1 = *(const uint2*)(coeff + u_rel * 512 + ((ep * 2 + 1) * 16 + li) * 8);
    bf16x8 afS[2][2], afV[2][2];         // [rt][kj]
    #pragma unroll
    for (int rt = 0; rt < 2; ++rt)
      #pragma unroll
      for (int kj = 0; kj < 2; ++kj) {
        int off = (rt * 16 + li) * 128 + (((kj * 4 + lg) ^ (li & 7)) << 4);
        afS[rt][kj] = *(const bf16x8*)(afb + off);
        afV[rt][kj] = *(const bf16x8*)(afb + 4096 + off);
      }
    #pragma unroll
    for (int t2 = 0; t2 < 2; ++t2) {
      uint2 cf = t2 ? cf1 : cf0;
      float ms = bflo(cf.x), m0 = bfhi(cf.x), m1 = bflo(cf.y), m2 = bfhi(cf.y);
      #pragma unroll
      for (int rt = 0; rt < 2; ++rt) {
        f32x4 c = {0.f,0.f,0.f,0.f};
        c = MFMA16(afS[rt][0], bb[t2][0], c);
        c = MFMA16(afS[rt][1], bb[t2][1], c);
        aS[t2][rt] += ms * c;
        f32x4 d = {0.f,0.f,0.f,0.f};
        d = MFMA16(afV[rt][0], bb[t2][0], d);
        d = MFMA16(afV[rt][1], bb[t2][1], d);
        aV[t2][rt][0] += m0 * d;
        aV[t2][rt][1] += m1 * d;
        aV[t2][rt][2] += m2 * d;
      }
    }
  };

  // node branch: prefetch blocks 0,1; coeffs; then counted-vmcnt pipeline
  stage(0, 0, 0);
  stage(1, 0, 1);
  q_phase(nsrc, ndst, 2, ws + WS_TN, 64);
  __syncthreads();                 // coeff(node) visible; vmcnt drained (both bufs landed)

  #pragma unroll 1
  for (int b = 0; b < 32; ++b) {
    main_block(b & 1, b, bbN);
    BARRIER();                     // all waves done reading buf[b&1]
    if (b < 30)      stage(b & 1, 0, b + 2);
    else             stage(b & 1, 1, b - 30);   // cross-branch prefetch edge b0/b1
    WAIT_VM4();                    // stage(b+1) landed; stage(b+2) stays in flight
    BARRIER();
  }

  // edge branch
  q_phase(efeat, efeat, 1, ws + WS_TE, 32);
  __syncthreads();                 // coeff(edge) visible; edge bufs 0,1 landed

  #pragma unroll 1
  for (int b = 0; b < 32; ++b) {
    main_block(b & 1, b, bbE);
    BARRIER();
    if (b < 30) stage(b & 1, 1, b + 2);
    WAIT_VM4();
    BARRIER();
  }

  // ---------------- cross-wave reduction into R1 (= coeff region) ----------------
  char* R1 = lds;
  auto rmw = [&](bool add) {
    #pragma unroll
    for (int t2 = 0; t2 < 2; ++t2) {
      int e = (ep * 2 + t2) * 16 + li;
      char* epp = R1 + e * 512;
      #pragma unroll
      for (int rt = 0; rt < 2; ++rt) {
        f32x4 s = aS[t2][rt];
        char* p = epp + (((rt * 4 + lg) ^ (e & 7)) << 4);
        if (add) s += *(const f32x4*)p;
        *(f32x4*)p = s;
        #pragma unroll
        for (int m = 0; m < 3; ++m) {
          f32x4 x = aV[t2][rt][m];
          char* q = epp + (((8 + m * 8 + rt * 4 + lg) ^ (e & 7)) << 4);
          if (add) x += *(const f32x4*)q;
          *(f32x4*)q = x;
        }
      }
    }
  };
  if (uh == 0) rmw(false);
  __syncthreads();
  if (uh == 1) rmw(true);
  __syncthreads();

  // ---------------- coalesced store (permute [S | V[m][w]] -> [s | v[w][m]]) ----------------
  #pragma unroll
  for (int it = 0; it < 8; ++it) {
    int chunk = it * 256 + tid;        // 2048 float4 chunks = 64 edges * 128 floats
    int e = chunk >> 5, c4 = chunk & 31;
    f32x4 v;
    #pragma unroll
    for (int q = 0; q < 4; ++q) {
      int f = c4 * 4 + q;
      int g, wd;
      if (f < 32) { g = f >> 2; wd = f & 3; }
      else { int t = f - 32; int w = t / 3; int m = t - w * 3; g = 8 + m * 8 + (w >> 2); wd = w & 3; }
      v[q] = *(const float*)(R1 + e * 512 + ((g ^ (e & 7)) << 4) + wd * 4);
    }
    int ge = ebase + e;
    if (ge < E) *(f32x4*)(out + (size_t)ge * 128 + c4 * 4) = v;
  }
}

extern "C" void kernel_launch(void* const* d_in, const int* in_sizes, int n_in,
                              void* d_out, int out_size, void* d_ws, size_t ws_size,
                              hipStream_t stream) {
  const float* nsrc  = (const float*)d_in[0];
  const float* ndst  = (const float*)d_in[1];
  const float* efeat = (const float*)d_in[2];
  const float* lenv  = (const float*)d_in[3];
  const float* escal = (const float*)d_in[4];
  const float* Wn1 = (const float*)d_in[5];
  const float* Wn2 = (const float*)d_in[6];
  const float* Wn3 = (const float*)d_in[7];
  const float* Wn4 = (const float*)d_in[8];
  const float* We1 = (const float*)d_in[9];
  const float* We2 = (const float*)d_in[10];
  const float* We3 = (const float*)d_in[11];
  const float* We4 = (const float*)d_in[12];
  const float* Mn1 = (const float*)d_in[13];
  const float* Mn2 = (const float*)d_in[14];
  const float* Mn3 = (const float*)d_in[15];
  const float* Me1 = (const float*)d_in[16];
  const float* Me2 = (const float*)d_in[17];
  const float* Me3 = (const float*)d_in[18];
  const float* Lns = (const float*)d_in[19];
  const float* Lnv = (const float*)d_in[20];
  const float* Les = (const float*)d_in[21];
  const float* Lev = (const float*)d_in[22];
  (void)n_in; (void)ws_size;

  int E = in_sizes[0] / 128;
  __bf16* ws = (__bf16*)d_ws;
  float* outp = (float*)d_out;
  (void)out_size;

  int nprep = (WS_CNT + 255) / 256;
  hipLaunchKernelGGL(prep_kernel, dim3(nprep), dim3(256), 0, stream,
                     Wn1, Wn2, Wn3, Wn4, We1, We2, We3, We4,
                     Mn1, Mn2, Mn3, Me1, Me2, Me3,
                     Lns, Lnv, Les, Lev, ws);

  int nwg = (E + 63) / 64;
  hipLaunchKernelGGL(fused_kernel, dim3(nwg), dim3(256), 0, stream,
                     nsrc, ndst, efeat, lenv, escal, ws, outp, E);
}